// Round 1
// 855.951 us; speedup vs baseline: 1.1110x; 1.1110x over previous
//
#include <hip/hip_runtime.h>
#include <cstdint>
#include <cstddef>

typedef unsigned short u16;
typedef unsigned int u32;
typedef __attribute__((ext_vector_type(8))) short short8;
typedef __attribute__((ext_vector_type(4))) float floatx4;

#define NROWS 38400   // B*T = 64*600

// ---- workspace layout (bytes) ----
#define OFF_FLAG 0u
#define OFF_GI   64u           // [2][38400][120] f32 = 36,864,000
#define OFF_HCAT 36864064u     // [38400][80] f32    = 12,288,000
#define OFF_B1A  49152064u     // [256][576] bf16    =    294,912
#define OFF_B1B  49446976u     // [256][576] bf16    =    294,912
#define OFF_B2   49741888u     // [80][1472] bf16    =    235,520
#define OFF_B3   49977408u     // [272][1472] bf16   =    800,768  (end ~50.78 MB)
#define OFF_KO   OFF_GI        // kan1out [38400][80] f32 overlays dead GI

__device__ inline float bf2f(u16 u){ union{u32 i; float f;} v; v.i = ((u32)u)<<16; return v.f; }
__device__ inline u16 f2bf(float f){
  u32 u = __float_as_uint(f);
  return (u16)((u + 0x7FFFu + ((u>>16)&1u)) >> 16);   // RNE
}
__device__ inline float lodf(const void* p, size_t i, int isbf){
  return isbf ? bf2f(((const u16*)p)[i]) : ((const float*)p)[i];
}
__device__ inline float rcpf(float x){ return __builtin_amdgcn_rcpf(x); }
__device__ inline float sigm(float x){ return rcpf(1.0f+__expf(-x)); }
__device__ inline float tanh_(float x){
  float e = __expf(-2.0f*fabsf(x)); float t = (1.0f-e)*rcpf(1.0f+e); return x<0.f ? -t : t;
}
__device__ inline float rdl(float v, int k){ return __int_as_float(__builtin_amdgcn_readlane(__float_as_int(v), k)); }

// ============================= detect input dtype (bf16 vs f32) =============================
__global__ void detect_kernel(const u16* __restrict__ xx, int* __restrict__ flag){
  const int l = threadIdx.x;
  const u16 w = xx[2*l];
  const int e = (w>>7)&0xFF;
  const unsigned long long m = __ballot(e >= 100 && e <= 133);
  if (l == 0) *flag = (__popcll(m) >= 32) ? 1 : 0;   // 1 = bf16
}

// ============================= prep: build padded bf16 B^T matrices =============================
__global__ void prep_kernel(const void* __restrict__ f0Wih, const void* __restrict__ b0Wih,
                            const void* __restrict__ k1b, const void* __restrict__ k1s, const void* __restrict__ k1sc,
                            const void* __restrict__ k2b, const void* __restrict__ k2s, const void* __restrict__ k2sc,
                            const int* __restrict__ flag,
                            u16* __restrict__ B1a, u16* __restrict__ B1b,
                            u16* __restrict__ B2, u16* __restrict__ B3)
{
  const int isbf = *flag;
  const int idx = blockIdx.x*256 + threadIdx.x;
  if (idx < 73728){
    const int j = idx/288, k = idx - j*288;
    float w = 0.f;
    if (k < 257 && j < 240)
      w = (j < 120) ? lodf(f0Wih, (size_t)j*257+k, isbf) : lodf(b0Wih, (size_t)(j-120)*257+k, isbf);
    const u16 hi = f2bf(w); const u16 lo = f2bf(w - bf2f(hi));
    B1a[(size_t)j*576 + 2*k] = hi; B1a[(size_t)j*576 + 2*k+1] = hi;
    B1b[(size_t)j*576 + 2*k] = lo; B1b[(size_t)j*576 + 2*k+1] = 0;
  } else if (idx < 132608){
    const int t = idx - 73728; const int n = t/736, m = t - n*736;
    float v = 0.f;
    if (m < 80) v = lodf(k1b, (size_t)n*80+m, isbf);
    else if (m >= 96){ const int m2 = m-96, i = m2>>3, g = m2&7;
      v = lodf(k1s, ((size_t)n*80+i)*8+g, isbf) * lodf(k1sc, (size_t)n*80+i, isbf); }
    const u16 vv = f2bf(v);
    B2[(size_t)n*1472 + 2*m] = vv; B2[(size_t)n*1472 + 2*m+1] = vv;
  } else {
    const int t = idx - 132608; const int n = t/736, m = t - n*736;
    float v = 0.f;
    if (n < 257){
      if (m < 80) v = lodf(k2b, (size_t)n*80+m, isbf);
      else if (m >= 96){ const int m2 = m-96, i = m2>>3, g = m2&7;
        v = lodf(k2s, ((size_t)n*80+i)*8+g, isbf) * lodf(k2sc, (size_t)n*80+i, isbf); }
    }
    const u16 vv = f2bf(v);
    B3[(size_t)n*1472 + 2*m] = vv; B3[(size_t)n*1472 + 2*m+1] = vv;
  }
}

// ============================= G1: gi = x @ Wih^T + bih, MFMA, nt-split across waves =============================
__launch_bounds__(256)
__global__ void g1_kernel(const void* __restrict__ x, const u16* __restrict__ B1a, const u16* __restrict__ B1b,
                          const void* __restrict__ f0bih, const void* __restrict__ b0bih,
                          const int* __restrict__ flag, float* __restrict__ gi)
{
  __shared__ __attribute__((aligned(16))) u16 As[32][576];
  const int isbf = *flag;
  const int tid = threadIdx.x;
  const size_t r0 = (size_t)blockIdx.x * 32;
  {
    const int row = tid>>3, kk = tid&7;
    #pragma unroll
    for (int it=0; it<36; ++it){
      const int k = kk + it*8;
      const float v = (k < 257) ? lodf(x, (r0+row)*257 + k, isbf) : 0.f;
      const u16 hi = f2bf(v);
      As[row][2*k] = hi; As[row][2*k+1] = f2bf(v - bf2f(hi));
    }
  }
  __syncthreads();
  const int w = tid>>6, l = tid&63, m16 = l&15, q4 = l>>4;
  // NT=15 split {4,4,4,3}
  const int cnt = (w<3)?4:3;
  const int ntlo = w*4;
  floatx4 acc[4][2];
  #pragma unroll
  for (int j=0;j<4;++j) for (int s=0;s<2;++s){ floatx4 z={0.f,0.f,0.f,0.f}; acc[j][s]=z; }
  #pragma unroll 1
  for (int ks=0; ks<18; ++ks){
    const short8 a0 = *(const short8*)&As[m16][ks*32 + q4*8];
    const short8 a1 = *(const short8*)&As[16+m16][ks*32 + q4*8];
    #pragma unroll
    for (int j=0;j<4;++j){
      if (j < cnt){
        const int nt = ntlo + j;
        const short8 ba = *(const short8*)&B1a[(size_t)(nt*16+m16)*576 + ks*32 + q4*8];
        acc[j][0] = __builtin_amdgcn_mfma_f32_16x16x32_bf16(a0, ba, acc[j][0], 0, 0, 0);
        acc[j][1] = __builtin_amdgcn_mfma_f32_16x16x32_bf16(a1, ba, acc[j][1], 0, 0, 0);
        if (!isbf){
          const short8 bb = *(const short8*)&B1b[(size_t)(nt*16+m16)*576 + ks*32 + q4*8];
          acc[j][0] = __builtin_amdgcn_mfma_f32_16x16x32_bf16(a0, bb, acc[j][0], 0, 0, 0);
          acc[j][1] = __builtin_amdgcn_mfma_f32_16x16x32_bf16(a1, bb, acc[j][1], 0, 0, 0);
        }
      }
    }
  }
  #pragma unroll
  for (int j=0;j<4;++j){
    if (j < cnt){
      const int col = (ntlo+j)*16 + m16;
      if (col < 240){
        const int dsel = (col < 120) ? 0 : 1;
        const int jj = (col < 120) ? col : col-120;
        const float bias = (col < 120) ? lodf(f0bih, col, isbf) : lodf(b0bih, col-120, isbf);
        #pragma unroll
        for (int s=0;s<2;++s){
          #pragma unroll
          for (int rg=0; rg<4; ++rg){
            const size_t row = r0 + s*16 + q4*4 + rg;
            gi[((size_t)dsel*NROWS + row)*120 + jj] = acc[j][s][rg] + bias;
          }
        }
      }
    }
  }
}

// ============================= GRU =============================
// Wave-specialized: each wave role gets its OWN loop (same barrier count per wave),
// so the 120 f32 weights of the compute waves stay in VGPRs instead of spilling to
// scratch (the shared-loop version allocated only 104 VGPRs -> per-cell scratch
// reloads dominated the runtime).
__device__ inline void stage_chunk32(const char* __restrict__ gid, int4* dst, int c, int d, int bat, int l)
{
  const long long rbase = (long long)bat*600 + (d ? (568 - 32*c) : (32*c));
  const long long base = rbase * 480;
  const long long lim = (long long)NROWS * 480;
  int4 v[15];
  #pragma unroll
  for (int j=0; j<15; ++j){
    const long long off = base + (long long)(j*64 + l)*16;
    int4 z; z.x=0; z.y=0; z.z=0; z.w=0;
    v[j] = (off >= 0 && off+16 <= lim) ? *(const int4*)(gid + off) : z;
  }
  #pragma unroll
  for (int j=0; j<15; ++j) dst[j*64 + l] = v[j];
}

__launch_bounds__(256, 1)
__global__ void gru_kernel(const float* __restrict__ gi,
  const void* __restrict__ f0Whh, const void* __restrict__ f0bhh,
  const void* __restrict__ f1Wih, const void* __restrict__ f1Whh, const void* __restrict__ f1bih, const void* __restrict__ f1bhh,
  const void* __restrict__ b0Whh, const void* __restrict__ b0bhh,
  const void* __restrict__ b1Wih, const void* __restrict__ b1Whh, const void* __restrict__ b1bih, const void* __restrict__ b1bhh,
  const int* __restrict__ flag, float* __restrict__ hcat)
{
  __shared__ int4 chunkbuf[2][960];          // 2 x 32 ticks x 120 f32 = 30720 B
  __shared__ float hbuf[2][64][40];          // hcat window buffer, 20480 B
  __shared__ float h0buf[2][2][40];
  __shared__ float gi1buf[2][2][3][40];
  const int isbf = *flag;
  const int tid = threadIdx.x, l = tid&63;
  // provably wave-uniform role id (SGPR) -> uniform branches around barriers
  const int w = __builtin_amdgcn_readfirstlane(tid) >> 6;
  const int blk = blockIdx.x, d = blk>>6, bat = blk&63;
  const int li = (l < 40) ? l : 39;
  const char* gid = (const char*)(gi + (size_t)d*NROWS*120);

  if (w == 3){
    // ---------------- stager / flusher wave ----------------
    stage_chunk32(gid, &chunkbuf[0][0], 0, d, bat, l);
    __syncthreads();
    #pragma unroll 1
    for (int i=0; i<302; ++i){
      if ((i & 15) == 0){ const int c1 = (i>>4) + 1; if (c1 <= 18) stage_chunk32(gid, &chunkbuf[c1&1][0], c1, d, bat, l); }
      if ((i & 31) == 2){ // flush hcat window m-1 (64 ticks)
        const int m = i>>5;
        if (m >= 1){
          const int t0 = 64*(m-1);
          const int4* src = (const int4*)&hbuf[(m-1)&1][0][0];
          #pragma unroll
          for (int q=0; q<10; ++q){
            const int f = q*64 + l;
            const int t = f/10, j4 = f - 10*t;
            int4 v = src[t*10 + j4];
            *(int4*)&hcat[((size_t)bat*600 + t0 + t)*80 + d*40 + j4*4] = v;
          }
        }
      }
      __syncthreads();
    }
  } else {
    // ---------------- compute waves: load role weights into VGPRs ----------------
    const void *Wsrc = 0, *bsrc = 0;
    if (w == 0){ Wsrc = d ? b0Whh : f0Whh; bsrc = d ? b0bhh : f0bhh; }
    else if (w == 1){ Wsrc = d ? b1Wih : f1Wih; bsrc = d ? b1bih : f1bih; }
    else { Wsrc = d ? b1Whh : f1Whh; bsrc = d ? b1bhh : f1bhh; }

    float WA[40], WB[40], WC[40];
    #pragma unroll
    for (int k=0; k<40; ++k){
      WA[k] = lodf(Wsrc, (size_t)(     li)*40 + k, isbf);
      WB[k] = lodf(Wsrc, (size_t)(40 + li)*40 + k, isbf);
      WC[k] = lodf(Wsrc, (size_t)(80 + li)*40 + k, isbf);
    }
    float bA = lodf(bsrc, li, isbf), bB = lodf(bsrc, 40+li, isbf), bC = lodf(bsrc, 80+li, isbf);
    // pin weights into VGPRs (forbid remat of the loads)
    #pragma unroll
    for (int k=0; k<40; ++k){
      asm volatile("" : "+v"(WA[k]), "+v"(WB[k]), "+v"(WC[k]));
    }
    float hs = 0.f;

    auto cell = [&](float hsv, float gA, float gB, float gC) -> float {
      float ar = bA, az = bB, an = bC;
      #pragma unroll
      for (int k=0; k<40; ++k){ const float hk = rdl(hsv, k); ar += WA[k]*hk; az += WB[k]*hk; an += WC[k]*hk; }
      const float r = sigm(gA + ar), z = sigm(gB + az);
      const float n = tanh_(gC + r*an);
      return (1.f - z)*n + z*hsv;
    };
    auto mv3 = [&](float hsv, float& oa, float& ob, float& oc){
      float ar = bA, az = bB, an = bC;
      #pragma unroll
      for (int k=0; k<40; ++k){ const float hk = rdl(hsv, k); ar += WA[k]*hk; az += WB[k]*hk; an += WC[k]*hk; }
      oa = ar; ob = az; oc = an;
    };

    __syncthreads();

    if (w == 0){
      // layer0 cell wave: ticks 2i, 2i+1 at iteration i
      #pragma unroll 1
      for (int i=0; i<302; ++i){
        if (i < 300){
          const int cc = (i>>4)&1;
          const int ta = (2*i)&31;
          const float* base = (const float*)&chunkbuf[cc][0];
          const float* ra = base + (d ? (31-ta)   : ta  )*120;
          const float* rb = base + (d ? (31-ta-1) : ta+1)*120;
          const float gAa=ra[li], gBa=ra[40+li], gCa=ra[80+li];
          const float gAb=rb[li], gBb=rb[40+li], gCb=rb[80+li];
          hs = cell(hs, gAa, gBa, gCa);
          if (l < 40) h0buf[i&1][0][l] = hs;
          hs = cell(hs, gAb, gBb, gCb);
          if (l < 40) h0buf[i&1][1][l] = hs;
        }
        __syncthreads();
      }
    } else if (w == 1){
      // layer1 input-side wave: consumes wave0's pair from i-1
      #pragma unroll 1
      for (int i=0; i<302; ++i){
        if (i >= 1 && i <= 300){
          const int p = (i-1)&1;
          const float ha = h0buf[p][0][li];
          const float hb = h0buf[p][1][li];
          float a0,a1,a2, b0,b1,b2;
          mv3(ha, a0, a1, a2);
          mv3(hb, b0, b1, b2);
          if (l < 40){
            gi1buf[i&1][0][0][l]=a0; gi1buf[i&1][0][1][l]=a1; gi1buf[i&1][0][2][l]=a2;
            gi1buf[i&1][1][0][l]=b0; gi1buf[i&1][1][1][l]=b1; gi1buf[i&1][1][2][l]=b2;
          }
        }
        __syncthreads();
      }
    } else {
      // layer1 cell wave: ticks 2(i-2), 2(i-2)+1 at iteration i
      #pragma unroll 1
      for (int i=0; i<302; ++i){
        if (i >= 2){
          const int p = (i-1)&1;
          const float gAa=gi1buf[p][0][0][li], gBa=gi1buf[p][0][1][li], gCa=gi1buf[p][0][2][li];
          const float gAb=gi1buf[p][1][0][li], gBb=gi1buf[p][1][1][li], gCb=gi1buf[p][1][2][li];
          const int ta2 = 2*(i-2);
          const int wp = (ta2>>6)&1, sa = ta2&63;
          hs = cell(hs, gAa, gBa, gCa);
          if (l < 40) hbuf[wp][sa][l] = hs;
          hs = cell(hs, gAb, gBb, gCb);
          if (l < 40) hbuf[wp][sa+1][l] = hs;
        }
        __syncthreads();
      }
    }
  }
  // flush final window (ticks 576..599, parity (9&1)=1); all waves have passed the
  // final in-loop barrier (303 barriers each), so hbuf writes are visible.
  if (tid < 240){
    const int t = tid/10, j4 = tid - 10*t;
    const int4* src = (const int4*)&hbuf[1][0][0];
    int4 v = src[t*10 + j4];
    *(int4*)&hcat[((size_t)bat*600 + 576 + t)*80 + d*40 + j4*4] = v;
  }
}

// ============================= KAN: fused A-construction + MFMA, nt-split across waves =============================
__device__ inline void spline8(float x, float* bs)
{
  float g[12];
  #pragma unroll
  for (int j=0; j<12; ++j) g[j] = (float)(j-3)*0.4f - 1.0f;
  float b0[11];
  #pragma unroll
  for (int j=0; j<11; ++j) b0[j] = (x >= g[j] && x < g[j+1]) ? 1.f : 0.f;
  float b1[10];
  #pragma unroll
  for (int j=0; j<10; ++j)
    b1[j] = (x - g[j])*(1.0f/(g[j+1]-g[j]))*b0[j] + (g[j+2] - x)*(1.0f/(g[j+2]-g[j+1]))*b0[j+1];
  float b2[9];
  #pragma unroll
  for (int j=0; j<9; ++j)
    b2[j] = (x - g[j])*(1.0f/(g[j+2]-g[j]))*b1[j] + (g[j+3] - x)*(1.0f/(g[j+3]-g[j+1]))*b1[j+1];
  #pragma unroll
  for (int j=0; j<8; ++j)
    bs[j] = (x - g[j])*(1.0f/(g[j+3]-g[j]))*b2[j] + (g[j+4] - x)*(1.0f/(g[j+4]-g[j+1]))*b2[j+1];
}

template<int NT, bool FINAL>
__launch_bounds__(256)
__global__ void kan_kernel(const float* __restrict__ Xin, const u16* __restrict__ Bmat,
                           float* __restrict__ Yout, void* __restrict__ Obuf,
                           const void* __restrict__ slope, const int* __restrict__ flag)
{
  constexpr int MAXC = (NT+3)/4;
  __shared__ __attribute__((aligned(16))) float xs[64][80];
  __shared__ __attribute__((aligned(16))) u16 abase[64][192];
  __shared__ __attribute__((aligned(16))) u16 asp[64][128];
  const int isbf = *flag;
  const int tid = threadIdx.x;
  const size_t r0 = (size_t)blockIdx.x * 64;

  for (int idx=tid; idx<5120; idx+=256) ((float*)xs)[idx] = Xin[r0*80 + idx];
  __syncthreads();
  for (int idx=tid; idx<6144; idx+=256){
    const int row = idx/96, m = idx - row*96;
    float v = 0.f;
    if (m < 80){ const float xv = xs[row][m]; v = xv * sigm(xv); }
    const u16 hi = f2bf(v);
    abase[row][2*m] = hi; abase[row][2*m+1] = f2bf(v - bf2f(hi));
  }
  __syncthreads();

  const int w = tid>>6, l = tid&63, m16 = l&15, q4 = l>>4;
  const int cbase = NT>>2, rem = NT&3;
  const int cnt  = cbase + ((w < rem) ? 1 : 0);
  const int ntlo = w*cbase + ((w < rem) ? w : rem);
  floatx4 acc[MAXC][4];
  #pragma unroll
  for (int j=0;j<MAXC;++j) for (int s=0;s<4;++s){ floatx4 z={0.f,0.f,0.f,0.f}; acc[j][s]=z; }

  #pragma unroll 1
  for (int ks=0; ks<6; ++ks){
    short8 a[4];
    #pragma unroll
    for (int s=0;s<4;++s) a[s] = *(const short8*)&abase[s*16+m16][ks*32 + q4*8];
    #pragma unroll
    for (int j=0;j<MAXC;++j){
      if (j < cnt){
        const short8 b = *(const short8*)&Bmat[(size_t)((ntlo+j)*16+m16)*1472 + ks*32 + q4*8];
        #pragma unroll
        for (int s=0;s<4;++s) acc[j][s] = __builtin_amdgcn_mfma_f32_16x16x32_bf16(a[s], b, acc[j][s], 0, 0, 0);
      }
    }
  }
  #pragma unroll 1
  for (int c=0; c<10; ++c){
    __syncthreads();
    for (int idx=tid; idx<512; idx+=256){
      const int row = idx>>3, il = idx&7;
      const float xv = xs[row][c*8 + il];
      float bs[8]; spline8(xv, bs);
      union { u16 us[16]; short8 v2[2]; } pk;
      #pragma unroll
      for (int j=0; j<8; ++j){ const u16 hi = f2bf(bs[j]); pk.us[2*j] = hi; pk.us[2*j+1] = f2bf(bs[j] - bf2f(hi)); }
      *(short8*)&asp[row][il*16]     = pk.v2[0];
      *(short8*)&asp[row][il*16 + 8] = pk.v2[1];
    }
    __syncthreads();
    #pragma unroll 1
    for (int ks=0; ks<4; ++ks){
      short8 a[4];
      #pragma unroll
      for (int s=0;s<4;++s) a[s] = *(const short8*)&asp[s*16+m16][ks*32 + q4*8];
      const int kg = 192 + c*128 + ks*32 + q4*8;
      #pragma unroll
      for (int j=0;j<MAXC;++j){
        if (j < cnt){
          const short8 b = *(const short8*)&Bmat[(size_t)((ntlo+j)*16+m16)*1472 + kg];
          #pragma unroll
          for (int s=0;s<4;++s) acc[j][s] = __builtin_amdgcn_mfma_f32_16x16x32_bf16(a[s], b, acc[j][s], 0, 0, 0);
        }
      }
    }
  }

  #pragma unroll
  for (int j=0;j<MAXC;++j){
    if (j < cnt){
      const int col = (ntlo+j)*16 + m16;
      #pragma unroll
      for (int s=0;s<4;++s){
        #pragma unroll
        for (int rg=0; rg<4; ++rg){
          const size_t row = r0 + s*16 + q4*4 + rg;
          const float v = acc[j][s][rg];
          if constexpr (!FINAL){
            Yout[row*80 + col] = v;
          } else {
            if (col < 257){
              const float sl = lodf(slope, col, isbf);
              const float o = 1.2f * sigm(sl*v);
              if (isbf) ((u16*)Obuf)[row*257 + col] = f2bf(o);
              else      ((float*)Obuf)[row*257 + col] = o;
            }
          }
        }
      }
    }
  }
}

// ============================= launcher =============================
extern "C" void kernel_launch(void* const* d_in, const int* in_sizes, int n_in,
                              void* d_out, int out_size, void* d_ws, size_t ws_size,
                              hipStream_t stream)
{
  (void)in_sizes; (void)n_in; (void)out_size; (void)ws_size;
  const void* x     = d_in[0];
  const void* f0Wih = d_in[2];  const void* f0Whh = d_in[3];
  const void* f0bih = d_in[4];  const void* f0bhh = d_in[5];
  const void* f1Wih = d_in[6];  const void* f1Whh = d_in[7];
  const void* f1bih = d_in[8];  const void* f1bhh = d_in[9];
  const void* b0Wih = d_in[10]; const void* b0Whh = d_in[11];
  const void* b0bih = d_in[12]; const void* b0bhh = d_in[13];
  const void* b1Wih = d_in[14]; const void* b1Whh = d_in[15];
  const void* b1bih = d_in[16]; const void* b1bhh = d_in[17];
  const void* k1b   = d_in[18]; const void* k1s   = d_in[19]; const void* k1sc = d_in[20];
  const void* k2b   = d_in[21]; const void* k2s   = d_in[22]; const void* k2sc = d_in[23];
  const void* slope = d_in[24];

  char* ws = (char*)d_ws;
  int*   flag  = (int*)(ws + OFF_FLAG);
  float* gi    = (float*)(ws + OFF_GI);
  float* hcat  = (float*)(ws + OFF_HCAT);
  float* k1out = (float*)(ws + OFF_KO);
  u16* B1a = (u16*)(ws + OFF_B1A);
  u16* B1b = (u16*)(ws + OFF_B1B);
  u16* B2  = (u16*)(ws + OFF_B2);
  u16* B3  = (u16*)(ws + OFF_B3);

  detect_kernel<<<1, 64, 0, stream>>>((const u16*)x, flag);
  prep_kernel<<<1300, 256, 0, stream>>>(f0Wih, b0Wih, k1b, k1s, k1sc, k2b, k2s, k2sc, flag, B1a, B1b, B2, B3);
  g1_kernel<<<1200, 256, 0, stream>>>(x, B1a, B1b, f0bih, b0bih, flag, gi);
  gru_kernel<<<128, 256, 0, stream>>>(gi,
      f0Whh, f0bhh, f1Wih, f1Whh, f1bih, f1bhh,
      b0Whh, b0bhh, b1Wih, b1Whh, b1bih, b1bhh, flag, hcat);
  kan_kernel<5,  false><<<600, 256, 0, stream>>>(hcat, B2, k1out, nullptr, nullptr, flag);
  kan_kernel<17, true ><<<600, 256, 0, stream>>>(k1out, B3, nullptr, d_out, slope, flag);
}

// Round 2
// 853.178 us; speedup vs baseline: 1.1146x; 1.0033x over previous
//
#include <hip/hip_runtime.h>
#include <cstdint>
#include <cstddef>

typedef unsigned short u16;
typedef unsigned int u32;
typedef __attribute__((ext_vector_type(8))) short short8;
typedef __attribute__((ext_vector_type(4))) float floatx4;

#define NROWS 38400   // B*T = 64*600

// ---- workspace layout (bytes) ----
#define OFF_FLAG 0u
#define OFF_GI   64u           // [2][38400][120] f32 = 36,864,000
#define OFF_HCAT 36864064u     // [38400][80] f32    = 12,288,000
#define OFF_B1A  49152064u     // [256][576] bf16    =    294,912
#define OFF_B1B  49446976u     // [256][576] bf16    =    294,912
#define OFF_B2   49741888u     // [80][1472] bf16    =    235,520
#define OFF_B3   49977408u     // [272][1472] bf16   =    800,768  (end ~50.78 MB)
#define OFF_KO   OFF_GI        // kan1out [38400][80] f32 overlays dead GI

__device__ inline float bf2f(u16 u){ union{u32 i; float f;} v; v.i = ((u32)u)<<16; return v.f; }
__device__ inline u16 f2bf(float f){
  u32 u = __float_as_uint(f);
  return (u16)((u + 0x7FFFu + ((u>>16)&1u)) >> 16);   // RNE
}
__device__ inline float lodf(const void* p, size_t i, int isbf){
  return isbf ? bf2f(((const u16*)p)[i]) : ((const float*)p)[i];
}
__device__ inline float rcpf(float x){ return __builtin_amdgcn_rcpf(x); }
__device__ inline float sigm(float x){ return rcpf(1.0f+__expf(-x)); }
__device__ inline float tanh_(float x){
  float e = __expf(-2.0f*fabsf(x)); float t = (1.0f-e)*rcpf(1.0f+e); return x<0.f ? -t : t;
}
__device__ inline float rdl(float v, int k){ return __int_as_float(__builtin_amdgcn_readlane(__float_as_int(v), k)); }

// ============================= detect input dtype (bf16 vs f32) =============================
__global__ void detect_kernel(const u16* __restrict__ xx, int* __restrict__ flag){
  const int l = threadIdx.x;
  const u16 w = xx[2*l];
  const int e = (w>>7)&0xFF;
  const unsigned long long m = __ballot(e >= 100 && e <= 133);
  if (l == 0) *flag = (__popcll(m) >= 32) ? 1 : 0;   // 1 = bf16
}

// ============================= prep: build padded bf16 B^T matrices =============================
__global__ void prep_kernel(const void* __restrict__ f0Wih, const void* __restrict__ b0Wih,
                            const void* __restrict__ k1b, const void* __restrict__ k1s, const void* __restrict__ k1sc,
                            const void* __restrict__ k2b, const void* __restrict__ k2s, const void* __restrict__ k2sc,
                            const int* __restrict__ flag,
                            u16* __restrict__ B1a, u16* __restrict__ B1b,
                            u16* __restrict__ B2, u16* __restrict__ B3)
{
  const int isbf = *flag;
  const int idx = blockIdx.x*256 + threadIdx.x;
  if (idx < 73728){
    const int j = idx/288, k = idx - j*288;
    float w = 0.f;
    if (k < 257 && j < 240)
      w = (j < 120) ? lodf(f0Wih, (size_t)j*257+k, isbf) : lodf(b0Wih, (size_t)(j-120)*257+k, isbf);
    const u16 hi = f2bf(w); const u16 lo = f2bf(w - bf2f(hi));
    B1a[(size_t)j*576 + 2*k] = hi; B1a[(size_t)j*576 + 2*k+1] = hi;
    B1b[(size_t)j*576 + 2*k] = lo; B1b[(size_t)j*576 + 2*k+1] = 0;
  } else if (idx < 132608){
    const int t = idx - 73728; const int n = t/736, m = t - n*736;
    float v = 0.f;
    if (m < 80) v = lodf(k1b, (size_t)n*80+m, isbf);
    else if (m >= 96){ const int m2 = m-96, i = m2>>3, g = m2&7;
      v = lodf(k1s, ((size_t)n*80+i)*8+g, isbf) * lodf(k1sc, (size_t)n*80+i, isbf); }
    const u16 vv = f2bf(v);
    B2[(size_t)n*1472 + 2*m] = vv; B2[(size_t)n*1472 + 2*m+1] = vv;
  } else {
    const int t = idx - 132608; const int n = t/736, m = t - n*736;
    float v = 0.f;
    if (n < 257){
      if (m < 80) v = lodf(k2b, (size_t)n*80+m, isbf);
      else if (m >= 96){ const int m2 = m-96, i = m2>>3, g = m2&7;
        v = lodf(k2s, ((size_t)n*80+i)*8+g, isbf) * lodf(k2sc, (size_t)n*80+i, isbf); }
    }
    const u16 vv = f2bf(v);
    B3[(size_t)n*1472 + 2*m] = vv; B3[(size_t)n*1472 + 2*m+1] = vv;
  }
}

// ============================= G1: gi = x @ Wih^T + bih, MFMA, nt-split across waves =============================
__launch_bounds__(256)
__global__ void g1_kernel(const void* __restrict__ x, const u16* __restrict__ B1a, const u16* __restrict__ B1b,
                          const void* __restrict__ f0bih, const void* __restrict__ b0bih,
                          const int* __restrict__ flag, float* __restrict__ gi)
{
  __shared__ __attribute__((aligned(16))) u16 As[32][576];
  const int isbf = *flag;
  const int tid = threadIdx.x;
  const size_t r0 = (size_t)blockIdx.x * 32;
  {
    const int row = tid>>3, kk = tid&7;
    #pragma unroll
    for (int it=0; it<36; ++it){
      const int k = kk + it*8;
      const float v = (k < 257) ? lodf(x, (r0+row)*257 + k, isbf) : 0.f;
      const u16 hi = f2bf(v);
      As[row][2*k] = hi; As[row][2*k+1] = f2bf(v - bf2f(hi));
    }
  }
  __syncthreads();
  const int w = tid>>6, l = tid&63, m16 = l&15, q4 = l>>4;
  // NT=15 split {4,4,4,3}
  const int cnt = (w<3)?4:3;
  const int ntlo = w*4;
  floatx4 acc[4][2];
  #pragma unroll
  for (int j=0;j<4;++j) for (int s=0;s<2;++s){ floatx4 z={0.f,0.f,0.f,0.f}; acc[j][s]=z; }
  #pragma unroll 1
  for (int ks=0; ks<18; ++ks){
    const short8 a0 = *(const short8*)&As[m16][ks*32 + q4*8];
    const short8 a1 = *(const short8*)&As[16+m16][ks*32 + q4*8];
    #pragma unroll
    for (int j=0;j<4;++j){
      if (j < cnt){
        const int nt = ntlo + j;
        const short8 ba = *(const short8*)&B1a[(size_t)(nt*16+m16)*576 + ks*32 + q4*8];
        acc[j][0] = __builtin_amdgcn_mfma_f32_16x16x32_bf16(a0, ba, acc[j][0], 0, 0, 0);
        acc[j][1] = __builtin_amdgcn_mfma_f32_16x16x32_bf16(a1, ba, acc[j][1], 0, 0, 0);
        if (!isbf){
          const short8 bb = *(const short8*)&B1b[(size_t)(nt*16+m16)*576 + ks*32 + q4*8];
          acc[j][0] = __builtin_amdgcn_mfma_f32_16x16x32_bf16(a0, bb, acc[j][0], 0, 0, 0);
          acc[j][1] = __builtin_amdgcn_mfma_f32_16x16x32_bf16(a1, bb, acc[j][1], 0, 0, 0);
        }
      }
    }
  }
  #pragma unroll
  for (int j=0;j<4;++j){
    if (j < cnt){
      const int col = (ntlo+j)*16 + m16;
      if (col < 240){
        const int dsel = (col < 120) ? 0 : 1;
        const int jj = (col < 120) ? col : col-120;
        const float bias = (col < 120) ? lodf(f0bih, col, isbf) : lodf(b0bih, col-120, isbf);
        #pragma unroll
        for (int s=0;s<2;++s){
          #pragma unroll
          for (int rg=0; rg<4; ++rg){
            const size_t row = r0 + s*16 + q4*4 + rg;
            gi[((size_t)dsel*NROWS + row)*120 + jj] = acc[j][s][rg] + bias;
          }
        }
      }
    }
  }
}

// ============================= GRU =============================
// Wave-specialized with LOOP-CARRIED register pins: the empty asm over all 120
// weight values executes every iteration, making the weights loop-carried asm
// operands -> the compiler cannot sink/remat their loads into the loop body
// (the VGPR_Count=84 allocation of the previous version showed it was doing
// exactly that, re-streaming ~120 dwords/lane per cell from cache).
#define PIN_W() do { \
    _Pragma("unroll") \
    for (int k_ = 0; k_ < 40; ++k_) \
      asm volatile("" : "+v"(WA[k_]), "+v"(WB[k_]), "+v"(WC[k_])); \
    asm volatile("" : "+v"(bA), "+v"(bB), "+v"(bC)); \
  } while (0)

__device__ inline void stage_chunk32(const char* __restrict__ gid, int4* dst, int c, int d, int bat, int l)
{
  const long long rbase = (long long)bat*600 + (d ? (568 - 32*c) : (32*c));
  const long long base = rbase * 480;
  const long long lim = (long long)NROWS * 480;
  int4 v[15];
  #pragma unroll
  for (int j=0; j<15; ++j){
    const long long off = base + (long long)(j*64 + l)*16;
    int4 z; z.x=0; z.y=0; z.z=0; z.w=0;
    v[j] = (off >= 0 && off+16 <= lim) ? *(const int4*)(gid + off) : z;
  }
  #pragma unroll
  for (int j=0; j<15; ++j) dst[j*64 + l] = v[j];
}

__launch_bounds__(256, 1)
__global__ void gru_kernel(const float* __restrict__ gi,
  const void* __restrict__ f0Whh, const void* __restrict__ f0bhh,
  const void* __restrict__ f1Wih, const void* __restrict__ f1Whh, const void* __restrict__ f1bih, const void* __restrict__ f1bhh,
  const void* __restrict__ b0Whh, const void* __restrict__ b0bhh,
  const void* __restrict__ b1Wih, const void* __restrict__ b1Whh, const void* __restrict__ b1bih, const void* __restrict__ b1bhh,
  const int* __restrict__ flag, float* __restrict__ hcat)
{
  __shared__ int4 chunkbuf[2][960];          // 2 x 32 ticks x 120 f32 = 30720 B
  __shared__ float hbuf[2][64][40];          // hcat window buffer, 20480 B
  __shared__ float h0buf[2][2][40];
  __shared__ float gi1buf[2][2][3][40];
  const int isbf = *flag;
  const int tid = threadIdx.x, l = tid&63;
  // provably wave-uniform role id (SGPR) -> uniform branches around barriers
  const int w = __builtin_amdgcn_readfirstlane(tid) >> 6;
  const int blk = blockIdx.x, d = blk>>6, bat = blk&63;
  const int li = (l < 40) ? l : 39;
  const char* gid = (const char*)(gi + (size_t)d*NROWS*120);

  if (w == 3){
    // ---------------- stager / flusher wave ----------------
    stage_chunk32(gid, &chunkbuf[0][0], 0, d, bat, l);
    __syncthreads();
    #pragma unroll 1
    for (int i=0; i<302; ++i){
      if ((i & 15) == 0){ const int c1 = (i>>4) + 1; if (c1 <= 18) stage_chunk32(gid, &chunkbuf[c1&1][0], c1, d, bat, l); }
      if ((i & 31) == 2){ // flush hcat window m-1 (64 ticks)
        const int m = i>>5;
        if (m >= 1){
          const int t0 = 64*(m-1);
          const int4* src = (const int4*)&hbuf[(m-1)&1][0][0];
          #pragma unroll
          for (int q=0; q<10; ++q){
            const int f = q*64 + l;
            const int t = f/10, j4 = f - 10*t;
            int4 v = src[t*10 + j4];
            *(int4*)&hcat[((size_t)bat*600 + t0 + t)*80 + d*40 + j4*4] = v;
          }
        }
      }
      __syncthreads();
    }
  } else {
    // ---------------- compute waves: load role weights into VGPRs ----------------
    const void *Wsrc = 0, *bsrc = 0;
    if (w == 0){ Wsrc = d ? b0Whh : f0Whh; bsrc = d ? b0bhh : f0bhh; }
    else if (w == 1){ Wsrc = d ? b1Wih : f1Wih; bsrc = d ? b1bih : f1bih; }
    else { Wsrc = d ? b1Whh : f1Whh; bsrc = d ? b1bhh : f1bhh; }

    float WA[40], WB[40], WC[40];
    #pragma unroll
    for (int k=0; k<40; ++k){
      WA[k] = lodf(Wsrc, (size_t)(     li)*40 + k, isbf);
      WB[k] = lodf(Wsrc, (size_t)(40 + li)*40 + k, isbf);
      WC[k] = lodf(Wsrc, (size_t)(80 + li)*40 + k, isbf);
    }
    float bA = lodf(bsrc, li, isbf), bB = lodf(bsrc, 40+li, isbf), bC = lodf(bsrc, 80+li, isbf);
    float hs = 0.f;

    auto cell = [&](float hsv, float gA, float gB, float gC) -> float {
      float ar = bA, az = bB, an = bC;
      #pragma unroll
      for (int k=0; k<40; ++k){ const float hk = rdl(hsv, k); ar += WA[k]*hk; az += WB[k]*hk; an += WC[k]*hk; }
      const float r = sigm(gA + ar), z = sigm(gB + az);
      const float n = tanh_(gC + r*an);
      return (1.f - z)*n + z*hsv;
    };
    auto mv3 = [&](float hsv, float& oa, float& ob, float& oc){
      float ar = bA, az = bB, an = bC;
      #pragma unroll
      for (int k=0; k<40; ++k){ const float hk = rdl(hsv, k); ar += WA[k]*hk; az += WB[k]*hk; an += WC[k]*hk; }
      oa = ar; ob = az; oc = an;
    };

    __syncthreads();

    if (w == 0){
      // layer0 cell wave: ticks 2i, 2i+1 at iteration i
      #pragma unroll 1
      for (int i=0; i<302; ++i){
        PIN_W();   // loop-carried pin: weights must be VGPR-resident here every iter
        if (i < 300){
          const int cc = (i>>4)&1;
          const int ta = (2*i)&31;
          const float* base = (const float*)&chunkbuf[cc][0];
          const float* ra = base + (d ? (31-ta)   : ta  )*120;
          const float* rb = base + (d ? (31-ta-1) : ta+1)*120;
          const float gAa=ra[li], gBa=ra[40+li], gCa=ra[80+li];
          const float gAb=rb[li], gBb=rb[40+li], gCb=rb[80+li];
          hs = cell(hs, gAa, gBa, gCa);
          if (l < 40) h0buf[i&1][0][l] = hs;
          hs = cell(hs, gAb, gBb, gCb);
          if (l < 40) h0buf[i&1][1][l] = hs;
        }
        __syncthreads();
      }
    } else if (w == 1){
      // layer1 input-side wave: consumes wave0's pair from i-1
      #pragma unroll 1
      for (int i=0; i<302; ++i){
        PIN_W();
        if (i >= 1 && i <= 300){
          const int p = (i-1)&1;
          const float ha = h0buf[p][0][li];
          const float hb = h0buf[p][1][li];
          float a0,a1,a2, b0,b1,b2;
          mv3(ha, a0, a1, a2);
          mv3(hb, b0, b1, b2);
          if (l < 40){
            gi1buf[i&1][0][0][l]=a0; gi1buf[i&1][0][1][l]=a1; gi1buf[i&1][0][2][l]=a2;
            gi1buf[i&1][1][0][l]=b0; gi1buf[i&1][1][1][l]=b1; gi1buf[i&1][1][2][l]=b2;
          }
        }
        __syncthreads();
      }
    } else {
      // layer1 cell wave: ticks 2(i-2), 2(i-2)+1 at iteration i
      #pragma unroll 1
      for (int i=0; i<302; ++i){
        PIN_W();
        if (i >= 2){
          const int p = (i-1)&1;
          const float gAa=gi1buf[p][0][0][li], gBa=gi1buf[p][0][1][li], gCa=gi1buf[p][0][2][li];
          const float gAb=gi1buf[p][1][0][li], gBb=gi1buf[p][1][1][li], gCb=gi1buf[p][1][2][li];
          const int ta2 = 2*(i-2);
          const int wp = (ta2>>6)&1, sa = ta2&63;
          hs = cell(hs, gAa, gBa, gCa);
          if (l < 40) hbuf[wp][sa][l] = hs;
          hs = cell(hs, gAb, gBb, gCb);
          if (l < 40) hbuf[wp][sa+1][l] = hs;
        }
        __syncthreads();
      }
    }
  }
  // flush final window (ticks 576..599, parity (9&1)=1); all waves have passed the
  // final in-loop barrier (303 barriers each), so hbuf writes are visible.
  if (tid < 240){
    const int t = tid/10, j4 = tid - 10*t;
    const int4* src = (const int4*)&hbuf[1][0][0];
    int4 v = src[t*10 + j4];
    *(int4*)&hcat[((size_t)bat*600 + 576 + t)*80 + d*40 + j4*4] = v;
  }
}

// ============================= KAN: fused A-construction + MFMA, nt-split across waves =============================
__device__ inline void spline8(float x, float* bs)
{
  float g[12];
  #pragma unroll
  for (int j=0; j<12; ++j) g[j] = (float)(j-3)*0.4f - 1.0f;
  float b0[11];
  #pragma unroll
  for (int j=0; j<11; ++j) b0[j] = (x >= g[j] && x < g[j+1]) ? 1.f : 0.f;
  float b1[10];
  #pragma unroll
  for (int j=0; j<10; ++j)
    b1[j] = (x - g[j])*(1.0f/(g[j+1]-g[j]))*b0[j] + (g[j+2] - x)*(1.0f/(g[j+2]-g[j+1]))*b0[j+1];
  float b2[9];
  #pragma unroll
  for (int j=0; j<9; ++j)
    b2[j] = (x - g[j])*(1.0f/(g[j+2]-g[j]))*b1[j] + (g[j+3] - x)*(1.0f/(g[j+3]-g[j+1]))*b1[j+1];
  #pragma unroll
  for (int j=0; j<8; ++j)
    bs[j] = (x - g[j])*(1.0f/(g[j+3]-g[j]))*b2[j] + (g[j+4] - x)*(1.0f/(g[j+4]-g[j+1]))*b2[j+1];
}

template<int NT, bool FINAL>
__launch_bounds__(256)
__global__ void kan_kernel(const float* __restrict__ Xin, const u16* __restrict__ Bmat,
                           float* __restrict__ Yout, void* __restrict__ Obuf,
                           const void* __restrict__ slope, const int* __restrict__ flag)
{
  constexpr int MAXC = (NT+3)/4;
  __shared__ __attribute__((aligned(16))) float xs[64][80];
  __shared__ __attribute__((aligned(16))) u16 abase[64][192];
  __shared__ __attribute__((aligned(16))) u16 asp[64][128];
  const int isbf = *flag;
  const int tid = threadIdx.x;
  const size_t r0 = (size_t)blockIdx.x * 64;

  for (int idx=tid; idx<5120; idx+=256) ((float*)xs)[idx] = Xin[r0*80 + idx];
  __syncthreads();
  for (int idx=tid; idx<6144; idx+=256){
    const int row = idx/96, m = idx - row*96;
    float v = 0.f;
    if (m < 80){ const float xv = xs[row][m]; v = xv * sigm(xv); }
    const u16 hi = f2bf(v);
    abase[row][2*m] = hi; abase[row][2*m+1] = f2bf(v - bf2f(hi));
  }
  __syncthreads();

  const int w = tid>>6, l = tid&63, m16 = l&15, q4 = l>>4;
  const int cbase = NT>>2, rem = NT&3;
  const int cnt  = cbase + ((w < rem) ? 1 : 0);
  const int ntlo = w*cbase + ((w < rem) ? w : rem);
  floatx4 acc[MAXC][4];
  #pragma unroll
  for (int j=0;j<MAXC;++j) for (int s=0;s<4;++s){ floatx4 z={0.f,0.f,0.f,0.f}; acc[j][s]=z; }

  #pragma unroll 1
  for (int ks=0; ks<6; ++ks){
    short8 a[4];
    #pragma unroll
    for (int s=0;s<4;++s) a[s] = *(const short8*)&abase[s*16+m16][ks*32 + q4*8];
    #pragma unroll
    for (int j=0;j<MAXC;++j){
      if (j < cnt){
        const short8 b = *(const short8*)&Bmat[(size_t)((ntlo+j)*16+m16)*1472 + ks*32 + q4*8];
        #pragma unroll
        for (int s=0;s<4;++s) acc[j][s] = __builtin_amdgcn_mfma_f32_16x16x32_bf16(a[s], b, acc[j][s], 0, 0, 0);
      }
    }
  }
  #pragma unroll 1
  for (int c=0; c<10; ++c){
    __syncthreads();
    for (int idx=tid; idx<512; idx+=256){
      const int row = idx>>3, il = idx&7;
      const float xv = xs[row][c*8 + il];
      float bs[8]; spline8(xv, bs);
      union { u16 us[16]; short8 v2[2]; } pk;
      #pragma unroll
      for (int j=0; j<8; ++j){ const u16 hi = f2bf(bs[j]); pk.us[2*j] = hi; pk.us[2*j+1] = f2bf(bs[j] - bf2f(hi)); }
      *(short8*)&asp[row][il*16]     = pk.v2[0];
      *(short8*)&asp[row][il*16 + 8] = pk.v2[1];
    }
    __syncthreads();
    #pragma unroll 1
    for (int ks=0; ks<4; ++ks){
      short8 a[4];
      #pragma unroll
      for (int s=0;s<4;++s) a[s] = *(const short8*)&asp[s*16+m16][ks*32 + q4*8];
      const int kg = 192 + c*128 + ks*32 + q4*8;
      #pragma unroll
      for (int j=0;j<MAXC;++j){
        if (j < cnt){
          const short8 b = *(const short8*)&Bmat[(size_t)((ntlo+j)*16+m16)*1472 + kg];
          #pragma unroll
          for (int s=0;s<4;++s) acc[j][s] = __builtin_amdgcn_mfma_f32_16x16x32_bf16(a[s], b, acc[j][s], 0, 0, 0);
        }
      }
    }
  }

  #pragma unroll
  for (int j=0;j<MAXC;++j){
    if (j < cnt){
      const int col = (ntlo+j)*16 + m16;
      #pragma unroll
      for (int s=0;s<4;++s){
        #pragma unroll
        for (int rg=0; rg<4; ++rg){
          const size_t row = r0 + s*16 + q4*4 + rg;
          const float v = acc[j][s][rg];
          if constexpr (!FINAL){
            Yout[row*80 + col] = v;
          } else {
            if (col < 257){
              const float sl = lodf(slope, col, isbf);
              const float o = 1.2f * sigm(sl*v);
              if (isbf) ((u16*)Obuf)[row*257 + col] = f2bf(o);
              else      ((float*)Obuf)[row*257 + col] = o;
            }
          }
        }
      }
    }
  }
}

// ============================= launcher =============================
extern "C" void kernel_launch(void* const* d_in, const int* in_sizes, int n_in,
                              void* d_out, int out_size, void* d_ws, size_t ws_size,
                              hipStream_t stream)
{
  (void)in_sizes; (void)n_in; (void)out_size; (void)ws_size;
  const void* x     = d_in[0];
  const void* f0Wih = d_in[2];  const void* f0Whh = d_in[3];
  const void* f0bih = d_in[4];  const void* f0bhh = d_in[5];
  const void* f1Wih = d_in[6];  const void* f1Whh = d_in[7];
  const void* f1bih = d_in[8];  const void* f1bhh = d_in[9];
  const void* b0Wih = d_in[10]; const void* b0Whh = d_in[11];
  const void* b0bih = d_in[12]; const void* b0bhh = d_in[13];
  const void* b1Wih = d_in[14]; const void* b1Whh = d_in[15];
  const void* b1bih = d_in[16]; const void* b1bhh = d_in[17];
  const void* k1b   = d_in[18]; const void* k1s   = d_in[19]; const void* k1sc = d_in[20];
  const void* k2b   = d_in[21]; const void* k2s   = d_in[22]; const void* k2sc = d_in[23];
  const void* slope = d_in[24];

  char* ws = (char*)d_ws;
  int*   flag  = (int*)(ws + OFF_FLAG);
  float* gi    = (float*)(ws + OFF_GI);
  float* hcat  = (float*)(ws + OFF_HCAT);
  float* k1out = (float*)(ws + OFF_KO);
  u16* B1a = (u16*)(ws + OFF_B1A);
  u16* B1b = (u16*)(ws + OFF_B1B);
  u16* B2  = (u16*)(ws + OFF_B2);
  u16* B3  = (u16*)(ws + OFF_B3);

  detect_kernel<<<1, 64, 0, stream>>>((const u16*)x, flag);
  prep_kernel<<<1300, 256, 0, stream>>>(f0Wih, b0Wih, k1b, k1s, k1sc, k2b, k2s, k2sc, flag, B1a, B1b, B2, B3);
  g1_kernel<<<1200, 256, 0, stream>>>(x, B1a, B1b, f0bih, b0bih, flag, gi);
  gru_kernel<<<128, 256, 0, stream>>>(gi,
      f0Whh, f0bhh, f1Wih, f1Whh, f1bih, f1bhh,
      b0Whh, b0bhh, b1Wih, b1Whh, b1bih, b1bhh, flag, hcat);
  kan_kernel<5,  false><<<600, 256, 0, stream>>>(hcat, B2, k1out, nullptr, nullptr, flag);
  kan_kernel<17, true ><<<600, 256, 0, stream>>>(k1out, B3, nullptr, d_out, slope, flag);
}

// Round 3
// 829.967 us; speedup vs baseline: 1.1458x; 1.0280x over previous
//
#include <hip/hip_runtime.h>
#include <cstdint>
#include <cstddef>

typedef unsigned short u16;
typedef unsigned int u32;
typedef __attribute__((ext_vector_type(8))) short short8;
typedef __attribute__((ext_vector_type(4))) float floatx4;

#define NROWS 38400   // B*T = 64*600

// ---- workspace layout (bytes) ----
#define OFF_FLAG 0u
#define OFF_GI   64u           // [2][38400][120] f32 = 36,864,000
#define OFF_HCAT 36864064u     // [38400][80] f32    = 12,288,000
#define OFF_B1A  49152064u     // [256][576] bf16    =    294,912
#define OFF_B1B  49446976u     // [256][576] bf16    =    294,912
#define OFF_B2   49741888u     // [80][1472] bf16    =    235,520
#define OFF_B3   49977408u     // [272][1472] bf16   =    800,768  (end ~50.78 MB)
#define OFF_KO   OFF_GI        // kan1out [38400][80] f32 overlays dead GI

__device__ inline float bf2f(u16 u){ union{u32 i; float f;} v; v.i = ((u32)u)<<16; return v.f; }
__device__ inline u16 f2bf(float f){
  u32 u = __float_as_uint(f);
  return (u16)((u + 0x7FFFu + ((u>>16)&1u)) >> 16);   // RNE
}
__device__ inline float lodf(const void* p, size_t i, int isbf){
  return isbf ? bf2f(((const u16*)p)[i]) : ((const float*)p)[i];
}
__device__ inline float rcpf(float x){ return __builtin_amdgcn_rcpf(x); }
__device__ inline float sigm(float x){ return rcpf(1.0f+__expf(-x)); }
__device__ inline float tanh_(float x){
  float e = __expf(-2.0f*fabsf(x)); float t = (1.0f-e)*rcpf(1.0f+e); return x<0.f ? -t : t;
}
__device__ inline float rdl(float v, int k){ return __int_as_float(__builtin_amdgcn_readlane(__float_as_int(v), k)); }

// ============================= detect input dtype (bf16 vs f32) =============================
__global__ void detect_kernel(const u16* __restrict__ xx, int* __restrict__ flag){
  const int l = threadIdx.x;
  const u16 w = xx[2*l];
  const int e = (w>>7)&0xFF;
  const unsigned long long m = __ballot(e >= 100 && e <= 133);
  if (l == 0) *flag = (__popcll(m) >= 32) ? 1 : 0;   // 1 = bf16
}

// ============================= prep: build padded bf16 B^T matrices =============================
__global__ void prep_kernel(const void* __restrict__ f0Wih, const void* __restrict__ b0Wih,
                            const void* __restrict__ k1b, const void* __restrict__ k1s, const void* __restrict__ k1sc,
                            const void* __restrict__ k2b, const void* __restrict__ k2s, const void* __restrict__ k2sc,
                            const int* __restrict__ flag,
                            u16* __restrict__ B1a, u16* __restrict__ B1b,
                            u16* __restrict__ B2, u16* __restrict__ B3)
{
  const int isbf = *flag;
  const int idx = blockIdx.x*256 + threadIdx.x;
  if (idx < 73728){
    const int j = idx/288, k = idx - j*288;
    float w = 0.f;
    if (k < 257 && j < 240)
      w = (j < 120) ? lodf(f0Wih, (size_t)j*257+k, isbf) : lodf(b0Wih, (size_t)(j-120)*257+k, isbf);
    const u16 hi = f2bf(w); const u16 lo = f2bf(w - bf2f(hi));
    B1a[(size_t)j*576 + 2*k] = hi; B1a[(size_t)j*576 + 2*k+1] = hi;
    B1b[(size_t)j*576 + 2*k] = lo; B1b[(size_t)j*576 + 2*k+1] = 0;
  } else if (idx < 132608){
    const int t = idx - 73728; const int n = t/736, m = t - n*736;
    float v = 0.f;
    if (m < 80) v = lodf(k1b, (size_t)n*80+m, isbf);
    else if (m >= 96){ const int m2 = m-96, i = m2>>3, g = m2&7;
      v = lodf(k1s, ((size_t)n*80+i)*8+g, isbf) * lodf(k1sc, (size_t)n*80+i, isbf); }
    const u16 vv = f2bf(v);
    B2[(size_t)n*1472 + 2*m] = vv; B2[(size_t)n*1472 + 2*m+1] = vv;
  } else {
    const int t = idx - 132608; const int n = t/736, m = t - n*736;
    float v = 0.f;
    if (n < 257){
      if (m < 80) v = lodf(k2b, (size_t)n*80+m, isbf);
      else if (m >= 96){ const int m2 = m-96, i = m2>>3, g = m2&7;
        v = lodf(k2s, ((size_t)n*80+i)*8+g, isbf) * lodf(k2sc, (size_t)n*80+i, isbf); }
    }
    const u16 vv = f2bf(v);
    B3[(size_t)n*1472 + 2*m] = vv; B3[(size_t)n*1472 + 2*m+1] = vv;
  }
}

// ============================= G1: gi = x @ Wih^T + bih, MFMA, nt-split across waves =============================
__launch_bounds__(256)
__global__ void g1_kernel(const void* __restrict__ x, const u16* __restrict__ B1a, const u16* __restrict__ B1b,
                          const void* __restrict__ f0bih, const void* __restrict__ b0bih,
                          const int* __restrict__ flag, float* __restrict__ gi)
{
  __shared__ __attribute__((aligned(16))) u16 As[32][576];
  const int isbf = *flag;
  const int tid = threadIdx.x;
  const size_t r0 = (size_t)blockIdx.x * 32;
  {
    const int row = tid>>3, kk = tid&7;
    #pragma unroll
    for (int it=0; it<36; ++it){
      const int k = kk + it*8;
      const float v = (k < 257) ? lodf(x, (r0+row)*257 + k, isbf) : 0.f;
      const u16 hi = f2bf(v);
      As[row][2*k] = hi; As[row][2*k+1] = f2bf(v - bf2f(hi));
    }
  }
  __syncthreads();
  const int w = tid>>6, l = tid&63, m16 = l&15, q4 = l>>4;
  // NT=15 split {4,4,4,3}
  const int cnt = (w<3)?4:3;
  const int ntlo = w*4;
  floatx4 acc[4][2];
  #pragma unroll
  for (int j=0;j<4;++j) for (int s=0;s<2;++s){ floatx4 z={0.f,0.f,0.f,0.f}; acc[j][s]=z; }
  #pragma unroll 1
  for (int ks=0; ks<18; ++ks){
    const short8 a0 = *(const short8*)&As[m16][ks*32 + q4*8];
    const short8 a1 = *(const short8*)&As[16+m16][ks*32 + q4*8];
    #pragma unroll
    for (int j=0;j<4;++j){
      if (j < cnt){
        const int nt = ntlo + j;
        const short8 ba = *(const short8*)&B1a[(size_t)(nt*16+m16)*576 + ks*32 + q4*8];
        acc[j][0] = __builtin_amdgcn_mfma_f32_16x16x32_bf16(a0, ba, acc[j][0], 0, 0, 0);
        acc[j][1] = __builtin_amdgcn_mfma_f32_16x16x32_bf16(a1, ba, acc[j][1], 0, 0, 0);
        if (!isbf){
          const short8 bb = *(const short8*)&B1b[(size_t)(nt*16+m16)*576 + ks*32 + q4*8];
          acc[j][0] = __builtin_amdgcn_mfma_f32_16x16x32_bf16(a0, bb, acc[j][0], 0, 0, 0);
          acc[j][1] = __builtin_amdgcn_mfma_f32_16x16x32_bf16(a1, bb, acc[j][1], 0, 0, 0);
        }
      }
    }
  }
  #pragma unroll
  for (int j=0;j<4;++j){
    if (j < cnt){
      const int col = (ntlo+j)*16 + m16;
      if (col < 240){
        const int dsel = (col < 120) ? 0 : 1;
        const int jj = (col < 120) ? col : col-120;
        const float bias = (col < 120) ? lodf(f0bih, col, isbf) : lodf(b0bih, col-120, isbf);
        #pragma unroll
        for (int s=0;s<2;++s){
          #pragma unroll
          for (int rg=0; rg<4; ++rg){
            const size_t row = r0 + s*16 + q4*4 + rg;
            gi[((size_t)dsel*NROWS + row)*120 + jj] = acc[j][s][rg] + bias;
          }
        }
      }
    }
  }
}

// ============================= GRU =============================
// Wave-specialized pipeline, 4 ticks per barrier period (was 2).
// R2 post-mortem: weights register-resident (VGPR 132) but dur unchanged ->
// the cost is per-PERIOD overhead (barrier rendezvous, LDS-latency injection,
// waitcnt drains), ~1300+ cy/period on top of ~700 cy compute. Amortize it:
// halve the number of periods by doing 4 ticks of the pipeline per barrier.
#define PIN_W() do { \
    _Pragma("unroll") \
    for (int k_ = 0; k_ < 40; ++k_) \
      asm volatile("" : "+v"(WA[k_]), "+v"(WB[k_]), "+v"(WC[k_])); \
    asm volatile("" : "+v"(bA), "+v"(bB), "+v"(bC)); \
  } while (0)

__device__ inline void stage_chunk32(const char* __restrict__ gid, int4* dst, int c, int d, int bat, int l)
{
  const long long rbase = (long long)bat*600 + (d ? (568 - 32*c) : (32*c));
  const long long base = rbase * 480;
  const long long lim = (long long)NROWS * 480;
  int4 v[15];
  #pragma unroll
  for (int j=0; j<15; ++j){
    const long long off = base + (long long)(j*64 + l)*16;
    int4 z; z.x=0; z.y=0; z.z=0; z.w=0;
    v[j] = (off >= 0 && off+16 <= lim) ? *(const int4*)(gid + off) : z;
  }
  #pragma unroll
  for (int j=0; j<15; ++j) dst[j*64 + l] = v[j];
}

__launch_bounds__(256, 1)
__global__ void gru_kernel(const float* __restrict__ gi,
  const void* __restrict__ f0Whh, const void* __restrict__ f0bhh,
  const void* __restrict__ f1Wih, const void* __restrict__ f1Whh, const void* __restrict__ f1bih, const void* __restrict__ f1bhh,
  const void* __restrict__ b0Whh, const void* __restrict__ b0bhh,
  const void* __restrict__ b1Wih, const void* __restrict__ b1Whh, const void* __restrict__ b1bih, const void* __restrict__ b1bhh,
  const int* __restrict__ flag, float* __restrict__ hcat)
{
  __shared__ int4 chunkbuf[2][960];          // 2 x 32 ticks x 120 f32 = 30720 B
  __shared__ float hbuf[2][64][40];          // hcat window buffer, 20480 B
  __shared__ float h0buf[2][4][40];          // 4 ticks per period
  __shared__ float gi1buf[2][4][3][40];
  const int isbf = *flag;
  const int tid = threadIdx.x, l = tid&63;
  // provably wave-uniform role id (SGPR) -> uniform branches around barriers
  const int w = __builtin_amdgcn_readfirstlane(tid) >> 6;
  const int blk = blockIdx.x, d = blk>>6, bat = blk&63;
  const int li = (l < 40) ? l : 39;
  const char* gid = (const char*)(gi + (size_t)d*NROWS*120);

  // Schedule (152 iterations, one barrier each; chunk = 32 ticks = 8 iters):
  //  w0: i<150        : layer0 cells for ticks 4i..4i+3   (reads chunkbuf[(i>>3)&1])
  //  w1: 1<=i<=150    : layer1 input matvec of h0buf[(i-1)&1]
  //  w2: i>=2         : layer1 cells for ticks 4(i-2)..+3 -> hbuf
  //  w3: (i&7)==0     : stage chunk (i>>3)+1 (<=18) into chunkbuf[((i>>3)+1)&1]
  //      (i&15)==2,i>=18: flush hcat window (i>>4)-1 (64 ticks) from hbuf
  if (w == 3){
    stage_chunk32(gid, &chunkbuf[0][0], 0, d, bat, l);
    __syncthreads();
    #pragma unroll 1
    for (int i=0; i<152; ++i){
      if ((i & 7) == 0){ const int c1 = (i>>3) + 1; if (c1 <= 18) stage_chunk32(gid, &chunkbuf[c1&1][0], c1, d, bat, l); }
      if ((i & 15) == 2 && i >= 18){
        const int m = (i>>4) - 1;        // window m: ticks 64m..64m+63, parity m&1
        const int t0 = 64*m;
        const int4* src = (const int4*)&hbuf[m&1][0][0];
        #pragma unroll
        for (int q=0; q<10; ++q){
          const int f = q*64 + l;
          const int t = f/10, j4 = f - 10*t;
          int4 v = src[t*10 + j4];
          *(int4*)&hcat[((size_t)bat*600 + t0 + t)*80 + d*40 + j4*4] = v;
        }
      }
      __syncthreads();
    }
  } else {
    // ---------------- compute waves: load role weights into VGPRs ----------------
    const void *Wsrc = 0, *bsrc = 0;
    if (w == 0){ Wsrc = d ? b0Whh : f0Whh; bsrc = d ? b0bhh : f0bhh; }
    else if (w == 1){ Wsrc = d ? b1Wih : f1Wih; bsrc = d ? b1bih : f1bih; }
    else { Wsrc = d ? b1Whh : f1Whh; bsrc = d ? b1bhh : f1bhh; }

    float WA[40], WB[40], WC[40];
    #pragma unroll
    for (int k=0; k<40; ++k){
      WA[k] = lodf(Wsrc, (size_t)(     li)*40 + k, isbf);
      WB[k] = lodf(Wsrc, (size_t)(40 + li)*40 + k, isbf);
      WC[k] = lodf(Wsrc, (size_t)(80 + li)*40 + k, isbf);
    }
    float bA = lodf(bsrc, li, isbf), bB = lodf(bsrc, 40+li, isbf), bC = lodf(bsrc, 80+li, isbf);
    float hs = 0.f;

    auto cell = [&](float hsv, float gA, float gB, float gC) -> float {
      float ar = bA, az = bB, an = bC;
      #pragma unroll
      for (int k=0; k<40; ++k){ const float hk = rdl(hsv, k); ar += WA[k]*hk; az += WB[k]*hk; an += WC[k]*hk; }
      const float r = sigm(gA + ar), z = sigm(gB + az);
      const float n = tanh_(gC + r*an);
      return (1.f - z)*n + z*hsv;
    };
    auto mv3 = [&](float hsv, float& oa, float& ob, float& oc){
      float ar = bA, az = bB, an = bC;
      #pragma unroll
      for (int k=0; k<40; ++k){ const float hk = rdl(hsv, k); ar += WA[k]*hk; az += WB[k]*hk; an += WC[k]*hk; }
      oa = ar; ob = az; oc = an;
    };

    __syncthreads();

    if (w == 0){
      // layer0 cell wave: ticks 4i..4i+3 at iteration i
      #pragma unroll 1
      for (int i=0; i<152; ++i){
        PIN_W();   // loop-carried pin: weights must be VGPR-resident every iter
        if (i < 150){
          const int cc = (i>>3)&1;
          const int ta = (4*i)&31;
          const float* base = (const float*)&chunkbuf[cc][0];
          #pragma unroll
          for (int t=0; t<4; ++t){
            const float* r = base + (d ? (31-(ta+t)) : (ta+t))*120;
            hs = cell(hs, r[li], r[40+li], r[80+li]);
            if (l < 40) h0buf[i&1][t][l] = hs;
          }
        }
        __syncthreads();
      }
    } else if (w == 1){
      // layer1 input-side wave: 4 independent matvecs of wave0's h0 from i-1
      #pragma unroll 1
      for (int i=0; i<152; ++i){
        PIN_W();
        if (i >= 1 && i <= 150){
          const int p = (i-1)&1;
          float oa[4], ob[4], oc[4];
          #pragma unroll
          for (int t=0; t<4; ++t){
            const float h0 = h0buf[p][t][li];
            mv3(h0, oa[t], ob[t], oc[t]);
          }
          if (l < 40){
            #pragma unroll
            for (int t=0; t<4; ++t){
              gi1buf[i&1][t][0][l]=oa[t]; gi1buf[i&1][t][1][l]=ob[t]; gi1buf[i&1][t][2][l]=oc[t];
            }
          }
        }
        __syncthreads();
      }
    } else {
      // layer1 cell wave: ticks 4(i-2)..+3 at iteration i
      #pragma unroll 1
      for (int i=0; i<152; ++i){
        PIN_W();
        if (i >= 2){
          const int p = (i-1)&1;
          const int ta2 = 4*(i-2);
          const int wp = (ta2>>6)&1, sa = ta2&63;
          #pragma unroll
          for (int t=0; t<4; ++t){
            hs = cell(hs, gi1buf[p][t][0][li], gi1buf[p][t][1][li], gi1buf[p][t][2][li]);
            if (l < 40) hbuf[wp][sa+t][l] = hs;
          }
        }
        __syncthreads();
      }
    }
  }
  // flush final window (window 9: ticks 576..599, parity 1); all waves have passed
  // the final in-loop barrier (153 barriers each), so hbuf writes are visible.
  if (tid < 240){
    const int t = tid/10, j4 = tid - 10*t;
    const int4* src = (const int4*)&hbuf[1][0][0];
    int4 v = src[t*10 + j4];
    *(int4*)&hcat[((size_t)bat*600 + 576 + t)*80 + d*40 + j4*4] = v;
  }
}

// ============================= KAN: fused A-construction + MFMA, nt-split across waves =============================
__device__ inline void spline8(float x, float* bs)
{
  float g[12];
  #pragma unroll
  for (int j=0; j<12; ++j) g[j] = (float)(j-3)*0.4f - 1.0f;
  float b0[11];
  #pragma unroll
  for (int j=0; j<11; ++j) b0[j] = (x >= g[j] && x < g[j+1]) ? 1.f : 0.f;
  float b1[10];
  #pragma unroll
  for (int j=0; j<10; ++j)
    b1[j] = (x - g[j])*(1.0f/(g[j+1]-g[j]))*b0[j] + (g[j+2] - x)*(1.0f/(g[j+2]-g[j+1]))*b0[j+1];
  float b2[9];
  #pragma unroll
  for (int j=0; j<9; ++j)
    b2[j] = (x - g[j])*(1.0f/(g[j+2]-g[j]))*b1[j] + (g[j+3] - x)*(1.0f/(g[j+3]-g[j+1]))*b1[j+1];
  #pragma unroll
  for (int j=0; j<8; ++j)
    bs[j] = (x - g[j])*(1.0f/(g[j+3]-g[j]))*b2[j] + (g[j+4] - x)*(1.0f/(g[j+4]-g[j+1]))*b2[j+1];
}

template<int NT, bool FINAL>
__launch_bounds__(256)
__global__ void kan_kernel(const float* __restrict__ Xin, const u16* __restrict__ Bmat,
                           float* __restrict__ Yout, void* __restrict__ Obuf,
                           const void* __restrict__ slope, const int* __restrict__ flag)
{
  constexpr int MAXC = (NT+3)/4;
  __shared__ __attribute__((aligned(16))) float xs[64][80];
  __shared__ __attribute__((aligned(16))) u16 abase[64][192];
  __shared__ __attribute__((aligned(16))) u16 asp[64][128];
  const int isbf = *flag;
  const int tid = threadIdx.x;
  const size_t r0 = (size_t)blockIdx.x * 64;

  for (int idx=tid; idx<5120; idx+=256) ((float*)xs)[idx] = Xin[r0*80 + idx];
  __syncthreads();
  for (int idx=tid; idx<6144; idx+=256){
    const int row = idx/96, m = idx - row*96;
    float v = 0.f;
    if (m < 80){ const float xv = xs[row][m]; v = xv * sigm(xv); }
    const u16 hi = f2bf(v);
    abase[row][2*m] = hi; abase[row][2*m+1] = f2bf(v - bf2f(hi));
  }
  __syncthreads();

  const int w = tid>>6, l = tid&63, m16 = l&15, q4 = l>>4;
  const int cbase = NT>>2, rem = NT&3;
  const int cnt  = cbase + ((w < rem) ? 1 : 0);
  const int ntlo = w*cbase + ((w < rem) ? w : rem);
  floatx4 acc[MAXC][4];
  #pragma unroll
  for (int j=0;j<MAXC;++j) for (int s=0;s<4;++s){ floatx4 z={0.f,0.f,0.f,0.f}; acc[j][s]=z; }

  #pragma unroll 1
  for (int ks=0; ks<6; ++ks){
    short8 a[4];
    #pragma unroll
    for (int s=0;s<4;++s) a[s] = *(const short8*)&abase[s*16+m16][ks*32 + q4*8];
    #pragma unroll
    for (int j=0;j<MAXC;++j){
      if (j < cnt){
        const short8 b = *(const short8*)&Bmat[(size_t)((ntlo+j)*16+m16)*1472 + ks*32 + q4*8];
        #pragma unroll
        for (int s=0;s<4;++s) acc[j][s] = __builtin_amdgcn_mfma_f32_16x16x32_bf16(a[s], b, acc[j][s], 0, 0, 0);
      }
    }
  }
  #pragma unroll 1
  for (int c=0; c<10; ++c){
    __syncthreads();
    for (int idx=tid; idx<512; idx+=256){
      const int row = idx>>3, il = idx&7;
      const float xv = xs[row][c*8 + il];
      float bs[8]; spline8(xv, bs);
      union { u16 us[16]; short8 v2[2]; } pk;
      #pragma unroll
      for (int j=0; j<8; ++j){ const u16 hi = f2bf(bs[j]); pk.us[2*j] = hi; pk.us[2*j+1] = f2bf(bs[j] - bf2f(hi)); }
      *(short8*)&asp[row][il*16]     = pk.v2[0];
      *(short8*)&asp[row][il*16 + 8] = pk.v2[1];
    }
    __syncthreads();
    #pragma unroll 1
    for (int ks=0; ks<4; ++ks){
      short8 a[4];
      #pragma unroll
      for (int s=0;s<4;++s) a[s] = *(const short8*)&asp[s*16+m16][ks*32 + q4*8];
      const int kg = 192 + c*128 + ks*32 + q4*8;
      #pragma unroll
      for (int j=0;j<MAXC;++j){
        if (j < cnt){
          const short8 b = *(const short8*)&Bmat[(size_t)((ntlo+j)*16+m16)*1472 + kg];
          #pragma unroll
          for (int s=0;s<4;++s) acc[j][s] = __builtin_amdgcn_mfma_f32_16x16x32_bf16(a[s], b, acc[j][s], 0, 0, 0);
        }
      }
    }
  }

  #pragma unroll
  for (int j=0;j<MAXC;++j){
    if (j < cnt){
      const int col = (ntlo+j)*16 + m16;
      #pragma unroll
      for (int s=0;s<4;++s){
        #pragma unroll
        for (int rg=0; rg<4; ++rg){
          const size_t row = r0 + s*16 + q4*4 + rg;
          const float v = acc[j][s][rg];
          if constexpr (!FINAL){
            Yout[row*80 + col] = v;
          } else {
            if (col < 257){
              const float sl = lodf(slope, col, isbf);
              const float o = 1.2f * sigm(sl*v);
              if (isbf) ((u16*)Obuf)[row*257 + col] = f2bf(o);
              else      ((float*)Obuf)[row*257 + col] = o;
            }
          }
        }
      }
    }
  }
}

// ============================= launcher =============================
extern "C" void kernel_launch(void* const* d_in, const int* in_sizes, int n_in,
                              void* d_out, int out_size, void* d_ws, size_t ws_size,
                              hipStream_t stream)
{
  (void)in_sizes; (void)n_in; (void)out_size; (void)ws_size;
  const void* x     = d_in[0];
  const void* f0Wih = d_in[2];  const void* f0Whh = d_in[3];
  const void* f0bih = d_in[4];  const void* f0bhh = d_in[5];
  const void* f1Wih = d_in[6];  const void* f1Whh = d_in[7];
  const void* f1bih = d_in[8];  const void* f1bhh = d_in[9];
  const void* b0Wih = d_in[10]; const void* b0Whh = d_in[11];
  const void* b0bih = d_in[12]; const void* b0bhh = d_in[13];
  const void* b1Wih = d_in[14]; const void* b1Whh = d_in[15];
  const void* b1bih = d_in[16]; const void* b1bhh = d_in[17];
  const void* k1b   = d_in[18]; const void* k1s   = d_in[19]; const void* k1sc = d_in[20];
  const void* k2b   = d_in[21]; const void* k2s   = d_in[22]; const void* k2sc = d_in[23];
  const void* slope = d_in[24];

  char* ws = (char*)d_ws;
  int*   flag  = (int*)(ws + OFF_FLAG);
  float* gi    = (float*)(ws + OFF_GI);
  float* hcat  = (float*)(ws + OFF_HCAT);
  float* k1out = (float*)(ws + OFF_KO);
  u16* B1a = (u16*)(ws + OFF_B1A);
  u16* B1b = (u16*)(ws + OFF_B1B);
  u16* B2  = (u16*)(ws + OFF_B2);
  u16* B3  = (u16*)(ws + OFF_B3);

  detect_kernel<<<1, 64, 0, stream>>>((const u16*)x, flag);
  prep_kernel<<<1300, 256, 0, stream>>>(f0Wih, b0Wih, k1b, k1s, k1sc, k2b, k2s, k2sc, flag, B1a, B1b, B2, B3);
  g1_kernel<<<1200, 256, 0, stream>>>(x, B1a, B1b, f0bih, b0bih, flag, gi);
  gru_kernel<<<128, 256, 0, stream>>>(gi,
      f0Whh, f0bhh, f1Wih, f1Whh, f1bih, f1bhh,
      b0Whh, b0bhh, b1Wih, b1Whh, b1bih, b1bhh, flag, hcat);
  kan_kernel<5,  false><<<600, 256, 0, stream>>>(hcat, B2, k1out, nullptr, nullptr, flag);
  kan_kernel<17, true ><<<600, 256, 0, stream>>>(k1out, B3, nullptr, d_out, slope, flag);
}

// Round 4
// 774.443 us; speedup vs baseline: 1.2279x; 1.0717x over previous
//
#include <hip/hip_runtime.h>
#include <cstdint>
#include <cstddef>

typedef unsigned short u16;
typedef unsigned int u32;
typedef __attribute__((ext_vector_type(8))) short short8;
typedef __attribute__((ext_vector_type(4))) float floatx4;

#define NROWS 38400   // B*T = 64*600

// ---- workspace layout (bytes) ----
#define OFF_FLAG 0u
#define OFF_GI   64u           // [2][38400][120] f32 = 36,864,000
#define OFF_HCAT 36864064u     // [38400][80] f32    = 12,288,000
#define OFF_B1A  49152064u     // [256][576] bf16    =    294,912
#define OFF_B1B  49446976u     // [256][576] bf16    =    294,912
#define OFF_B2   49741888u     // [80][1472] bf16    =    235,520
#define OFF_B3   49977408u     // [272][1472] bf16   =    800,768  (end ~50.78 MB)
#define OFF_KO   OFF_GI        // kan1out [38400][80] f32 overlays dead GI

__device__ inline float bf2f(u16 u){ union{u32 i; float f;} v; v.i = ((u32)u)<<16; return v.f; }
__device__ inline u16 f2bf(float f){
  u32 u = __float_as_uint(f);
  return (u16)((u + 0x7FFFu + ((u>>16)&1u)) >> 16);   // RNE
}
__device__ inline float lodf(const void* p, size_t i, int isbf){
  return isbf ? bf2f(((const u16*)p)[i]) : ((const float*)p)[i];
}
__device__ inline float rcpf(float x){ return __builtin_amdgcn_rcpf(x); }
__device__ inline float sigm(float x){ return rcpf(1.0f+__expf(-x)); }
__device__ inline float tanh_(float x){
  float e = __expf(-2.0f*fabsf(x)); float t = (1.0f-e)*rcpf(1.0f+e); return x<0.f ? -t : t;
}

// ============================= detect input dtype (bf16 vs f32) =============================
__global__ void detect_kernel(const u16* __restrict__ xx, int* __restrict__ flag){
  const int l = threadIdx.x;
  const u16 w = xx[2*l];
  const int e = (w>>7)&0xFF;
  const unsigned long long m = __ballot(e >= 100 && e <= 133);
  if (l == 0) *flag = (__popcll(m) >= 32) ? 1 : 0;   // 1 = bf16
}

// ============================= prep: build padded bf16 B^T matrices =============================
__global__ void prep_kernel(const void* __restrict__ f0Wih, const void* __restrict__ b0Wih,
                            const void* __restrict__ k1b, const void* __restrict__ k1s, const void* __restrict__ k1sc,
                            const void* __restrict__ k2b, const void* __restrict__ k2s, const void* __restrict__ k2sc,
                            const int* __restrict__ flag,
                            u16* __restrict__ B1a, u16* __restrict__ B1b,
                            u16* __restrict__ B2, u16* __restrict__ B3)
{
  const int isbf = *flag;
  const int idx = blockIdx.x*256 + threadIdx.x;
  if (idx < 73728){
    const int j = idx/288, k = idx - j*288;
    float w = 0.f;
    if (k < 257 && j < 240)
      w = (j < 120) ? lodf(f0Wih, (size_t)j*257+k, isbf) : lodf(b0Wih, (size_t)(j-120)*257+k, isbf);
    const u16 hi = f2bf(w); const u16 lo = f2bf(w - bf2f(hi));
    B1a[(size_t)j*576 + 2*k] = hi; B1a[(size_t)j*576 + 2*k+1] = hi;
    B1b[(size_t)j*576 + 2*k] = lo; B1b[(size_t)j*576 + 2*k+1] = 0;
  } else if (idx < 132608){
    const int t = idx - 73728; const int n = t/736, m = t - n*736;
    float v = 0.f;
    if (m < 80) v = lodf(k1b, (size_t)n*80+m, isbf);
    else if (m >= 96){ const int m2 = m-96, i = m2>>3, g = m2&7;
      v = lodf(k1s, ((size_t)n*80+i)*8+g, isbf) * lodf(k1sc, (size_t)n*80+i, isbf); }
    const u16 vv = f2bf(v);
    B2[(size_t)n*1472 + 2*m] = vv; B2[(size_t)n*1472 + 2*m+1] = vv;
  } else {
    const int t = idx - 132608; const int n = t/736, m = t - n*736;
    float v = 0.f;
    if (n < 257){
      if (m < 80) v = lodf(k2b, (size_t)n*80+m, isbf);
      else if (m >= 96){ const int m2 = m-96, i = m2>>3, g = m2&7;
        v = lodf(k2s, ((size_t)n*80+i)*8+g, isbf) * lodf(k2sc, (size_t)n*80+i, isbf); }
    }
    const u16 vv = f2bf(v);
    B3[(size_t)n*1472 + 2*m] = vv; B3[(size_t)n*1472 + 2*m+1] = vv;
  }
}

// ============================= G1: gi = x @ Wih^T + bih, MFMA, nt-split across waves =============================
__launch_bounds__(256)
__global__ void g1_kernel(const void* __restrict__ x, const u16* __restrict__ B1a, const u16* __restrict__ B1b,
                          const void* __restrict__ f0bih, const void* __restrict__ b0bih,
                          const int* __restrict__ flag, float* __restrict__ gi)
{
  __shared__ __attribute__((aligned(16))) u16 As[32][576];
  const int isbf = *flag;
  const int tid = threadIdx.x;
  const size_t r0 = (size_t)blockIdx.x * 32;
  {
    const int row = tid>>3, kk = tid&7;
    #pragma unroll
    for (int it=0; it<36; ++it){
      const int k = kk + it*8;
      const float v = (k < 257) ? lodf(x, (r0+row)*257 + k, isbf) : 0.f;
      const u16 hi = f2bf(v);
      As[row][2*k] = hi; As[row][2*k+1] = f2bf(v - bf2f(hi));
    }
  }
  __syncthreads();
  const int w = tid>>6, l = tid&63, m16 = l&15, q4 = l>>4;
  // NT=15 split {4,4,4,3}
  const int cnt = (w<3)?4:3;
  const int ntlo = w*4;
  floatx4 acc[4][2];
  #pragma unroll
  for (int j=0;j<4;++j) for (int s=0;s<2;++s){ floatx4 z={0.f,0.f,0.f,0.f}; acc[j][s]=z; }
  #pragma unroll 1
  for (int ks=0; ks<18; ++ks){
    const short8 a0 = *(const short8*)&As[m16][ks*32 + q4*8];
    const short8 a1 = *(const short8*)&As[16+m16][ks*32 + q4*8];
    #pragma unroll
    for (int j=0;j<4;++j){
      if (j < cnt){
        const int nt = ntlo + j;
        const short8 ba = *(const short8*)&B1a[(size_t)(nt*16+m16)*576 + ks*32 + q4*8];
        acc[j][0] = __builtin_amdgcn_mfma_f32_16x16x32_bf16(a0, ba, acc[j][0], 0, 0, 0);
        acc[j][1] = __builtin_amdgcn_mfma_f32_16x16x32_bf16(a1, ba, acc[j][1], 0, 0, 0);
        if (!isbf){
          const short8 bb = *(const short8*)&B1b[(size_t)(nt*16+m16)*576 + ks*32 + q4*8];
          acc[j][0] = __builtin_amdgcn_mfma_f32_16x16x32_bf16(a0, bb, acc[j][0], 0, 0, 0);
          acc[j][1] = __builtin_amdgcn_mfma_f32_16x16x32_bf16(a1, bb, acc[j][1], 0, 0, 0);
        }
      }
    }
  }
  #pragma unroll
  for (int j=0;j<4;++j){
    if (j < cnt){
      const int col = (ntlo+j)*16 + m16;
      if (col < 240){
        const int dsel = (col < 120) ? 0 : 1;
        const int jj = (col < 120) ? col : col-120;
        const float bias = (col < 120) ? lodf(f0bih, col, isbf) : lodf(b0bih, col-120, isbf);
        #pragma unroll
        for (int s=0;s<2;++s){
          #pragma unroll
          for (int rg=0; rg<4; ++rg){
            const size_t row = r0 + s*16 + q4*4 + rg;
            gi[((size_t)dsel*NROWS + row)*120 + jj] = acc[j][s][rg] + bias;
          }
        }
      }
    }
  }
}

// ============================= GRU =============================
// R3 post-mortem: period = 4C + B with C ~= 1390 cy/cell, B ~= 0. The cost is
// per-cell execution: ~570 cy busy (incl. readlane->SGPR->VALU wait states) +
// ~800 cy stall (just-in-time LDS gate-input reads under register squeeze,
// transcendental tail). This version: (1) LDS-BROADCAST matvec -- h state lives
// in a 160B LDS row, each cell reads it as 10x ds_read_b128 with wave-uniform
// addresses (broadcast, conflict-free); FMAs become pure-VGPR (no readlane, no
// SGPR hazards). (2) All per-period gate inputs hoisted into registers at body
// top (one LDS latency batch per period instead of per cell).
#define PIN_W() do { \
    _Pragma("unroll") \
    for (int k_ = 0; k_ < 40; ++k_) \
      asm volatile("" : "+v"(WA[k_]), "+v"(WB[k_]), "+v"(WC[k_])); \
    asm volatile("" : "+v"(bA), "+v"(bB), "+v"(bC)); \
  } while (0)

__device__ inline void stage_chunk32(const char* __restrict__ gid, int4* dst, int c, int d, int bat, int l)
{
  const long long rbase = (long long)bat*600 + (d ? (568 - 32*c) : (32*c));
  const long long base = rbase * 480;
  const long long lim = (long long)NROWS * 480;
  int4 v[15];
  #pragma unroll
  for (int j=0; j<15; ++j){
    const long long off = base + (long long)(j*64 + l)*16;
    int4 z; z.x=0; z.y=0; z.z=0; z.w=0;
    v[j] = (off >= 0 && off+16 <= lim) ? *(const int4*)(gid + off) : z;
  }
  #pragma unroll
  for (int j=0; j<15; ++j) dst[j*64 + l] = v[j];
}

__launch_bounds__(256, 1)
__global__ void gru_kernel(const float* __restrict__ gi,
  const void* __restrict__ f0Whh, const void* __restrict__ f0bhh,
  const void* __restrict__ f1Wih, const void* __restrict__ f1Whh, const void* __restrict__ f1bih, const void* __restrict__ f1bhh,
  const void* __restrict__ b0Whh, const void* __restrict__ b0bhh,
  const void* __restrict__ b1Wih, const void* __restrict__ b1Whh, const void* __restrict__ b1bih, const void* __restrict__ b1bhh,
  const int* __restrict__ flag, float* __restrict__ hcat)
{
  __shared__ int4 chunkbuf[2][960];                                   // 30720 B
  __shared__ __attribute__((aligned(16))) float hbuf[2][64][40];      // 20480 B
  __shared__ __attribute__((aligned(16))) float h0buf[2][4][40];      // 1280 B (rows 160B, 16B-aligned)
  __shared__ __attribute__((aligned(16))) float gi1buf[2][4][3][40];  // 3840 B
  __shared__ __attribute__((aligned(16))) float h0st[40];             // layer0 h state (broadcast row)
  __shared__ __attribute__((aligned(16))) float h1st[40];             // layer1 h state
  const int isbf = *flag;
  const int tid = threadIdx.x, l = tid&63;
  // provably wave-uniform role id (SGPR) -> uniform branches around barriers
  const int w = __builtin_amdgcn_readfirstlane(tid) >> 6;
  const int blk = blockIdx.x, d = blk>>6, bat = blk&63;
  const int li = (l < 40) ? l : 39;
  const char* gid = (const char*)(gi + (size_t)d*NROWS*120);

  // Schedule (152 iterations, one barrier each; chunk = 32 ticks = 8 iters):
  //  w0: i<150        : layer0 cells for ticks 4i..4i+3   (reads chunkbuf[(i>>3)&1])
  //  w1: 1<=i<=150    : layer1 input matvec of h0buf[(i-1)&1]
  //  w2: i>=2         : layer1 cells for ticks 4(i-2)..+3 -> hbuf
  //  w3: (i&7)==0     : stage chunk (i>>3)+1 (<=18); (i&15)==2,i>=18: flush hcat window
  if (w == 3){
    stage_chunk32(gid, &chunkbuf[0][0], 0, d, bat, l);
    __syncthreads();
    #pragma unroll 1
    for (int i=0; i<152; ++i){
      if ((i & 7) == 0){ const int c1 = (i>>3) + 1; if (c1 <= 18) stage_chunk32(gid, &chunkbuf[c1&1][0], c1, d, bat, l); }
      if ((i & 15) == 2 && i >= 18){
        const int m = (i>>4) - 1;        // window m: ticks 64m..64m+63, parity m&1
        const int t0 = 64*m;
        const int4* src = (const int4*)&hbuf[m&1][0][0];
        #pragma unroll
        for (int q=0; q<10; ++q){
          const int f = q*64 + l;
          const int t = f/10, j4 = f - 10*t;
          int4 v = src[t*10 + j4];
          *(int4*)&hcat[((size_t)bat*600 + t0 + t)*80 + d*40 + j4*4] = v;
        }
      }
      __syncthreads();
    }
  } else {
    // ---------------- compute waves: load role weights into VGPRs ----------------
    const void *Wsrc = 0, *bsrc = 0;
    if (w == 0){ Wsrc = d ? b0Whh : f0Whh; bsrc = d ? b0bhh : f0bhh; }
    else if (w == 1){ Wsrc = d ? b1Wih : f1Wih; bsrc = d ? b1bih : f1bih; }
    else { Wsrc = d ? b1Whh : f1Whh; bsrc = d ? b1bhh : f1bhh; }

    float WA[40], WB[40], WC[40];
    #pragma unroll
    for (int k=0; k<40; ++k){
      WA[k] = lodf(Wsrc, (size_t)(     li)*40 + k, isbf);
      WB[k] = lodf(Wsrc, (size_t)(40 + li)*40 + k, isbf);
      WC[k] = lodf(Wsrc, (size_t)(80 + li)*40 + k, isbf);
    }
    float bA = lodf(bsrc, li, isbf), bB = lodf(bsrc, 40+li, isbf), bC = lodf(bsrc, 80+li, isbf);
    float hs = 0.f;

    // broadcast matvec: h vector read from a 160B LDS row with wave-uniform
    // addresses (ds_read_b128 broadcast); all FMA operands are VGPRs.
    auto mv3B = [&](const float* hrow, float& oa, float& ob, float& oc){
      float ar = bA, az = bB, an = bC;
      #pragma unroll
      for (int kq=0; kq<10; ++kq){
        const floatx4 hv = *(const floatx4*)(hrow + kq*4);
        #pragma unroll
        for (int q=0; q<4; ++q){
          ar += WA[kq*4+q]*hv[q]; az += WB[kq*4+q]*hv[q]; an += WC[kq*4+q]*hv[q];
        }
      }
      oa = ar; ob = az; oc = an;
    };
    auto cellB = [&](const float* hrow, float hsv, float gA, float gB, float gC) -> float {
      float ar, az, an;
      mv3B(hrow, ar, az, an);
      const float r = sigm(gA + ar), z = sigm(gB + az);
      const float n = tanh_(gC + r*an);
      return (1.f - z)*n + z*hsv;
    };

    if (w == 0){
      if (l < 40) h0st[l] = 0.f;       // own-wave state init (no cross-wave reader)
      __syncthreads();
      #pragma unroll 1
      for (int i=0; i<152; ++i){
        PIN_W();
        if (i < 150){
          const int cc = (i>>3)&1;
          const int ta = (4*i)&31;
          const float* base = (const float*)&chunkbuf[cc][0];
          // hoist all 12 gate inputs for the period (one LDS latency batch)
          float gin[4][3];
          #pragma unroll
          for (int t=0; t<4; ++t){
            const float* r = base + (d ? (31-(ta+t)) : (ta+t))*120;
            gin[t][0]=r[li]; gin[t][1]=r[40+li]; gin[t][2]=r[80+li];
          }
          #pragma unroll
          for (int t=0; t<4; ++t){
            hs = cellB(h0st, hs, gin[t][0], gin[t][1], gin[t][2]);
            if (l < 40){ h0st[l] = hs; h0buf[i&1][t][l] = hs; }
          }
        }
        __syncthreads();
      }
    } else if (w == 1){
      __syncthreads();
      #pragma unroll 1
      for (int i=0; i<152; ++i){
        PIN_W();
        if (i >= 1 && i <= 150){
          const int p = (i-1)&1;
          #pragma unroll
          for (int t=0; t<4; ++t){
            float oa, ob, oc;
            mv3B(&h0buf[p][t][0], oa, ob, oc);
            if (l < 40){
              gi1buf[i&1][t][0][l]=oa; gi1buf[i&1][t][1][l]=ob; gi1buf[i&1][t][2][l]=oc;
            }
          }
        }
        __syncthreads();
      }
    } else {
      if (l < 40) h1st[l] = 0.f;
      __syncthreads();
      #pragma unroll 1
      for (int i=0; i<152; ++i){
        PIN_W();
        if (i >= 2){
          const int p = (i-1)&1;
          // hoist the 12 gate inputs (written by w1 last period; barrier between)
          float gin[4][3];
          #pragma unroll
          for (int t=0; t<4; ++t){
            gin[t][0]=gi1buf[p][t][0][li]; gin[t][1]=gi1buf[p][t][1][li]; gin[t][2]=gi1buf[p][t][2][li];
          }
          const int ta2 = 4*(i-2);
          const int wp = (ta2>>6)&1, sa = ta2&63;
          #pragma unroll
          for (int t=0; t<4; ++t){
            hs = cellB(h1st, hs, gin[t][0], gin[t][1], gin[t][2]);
            if (l < 40){ h1st[l] = hs; hbuf[wp][sa+t][l] = hs; }
          }
        }
        __syncthreads();
      }
    }
  }
  // flush final window (window 9: ticks 576..599, parity 1); all waves have passed
  // the final in-loop barrier (153 barriers each), so hbuf writes are visible.
  if (tid < 240){
    const int t = tid/10, j4 = tid - 10*t;
    const int4* src = (const int4*)&hbuf[1][0][0];
    int4 v = src[t*10 + j4];
    *(int4*)&hcat[((size_t)bat*600 + 576 + t)*80 + d*40 + j4*4] = v;
  }
}

// ============================= KAN: fused A-construction + MFMA, nt-split across waves =============================
__device__ inline void spline8(float x, float* bs)
{
  float g[12];
  #pragma unroll
  for (int j=0; j<12; ++j) g[j] = (float)(j-3)*0.4f - 1.0f;
  float b0[11];
  #pragma unroll
  for (int j=0; j<11; ++j) b0[j] = (x >= g[j] && x < g[j+1]) ? 1.f : 0.f;
  float b1[10];
  #pragma unroll
  for (int j=0; j<10; ++j)
    b1[j] = (x - g[j])*(1.0f/(g[j+1]-g[j]))*b0[j] + (g[j+2] - x)*(1.0f/(g[j+2]-g[j+1]))*b0[j+1];
  float b2[9];
  #pragma unroll
  for (int j=0; j<9; ++j)
    b2[j] = (x - g[j])*(1.0f/(g[j+2]-g[j]))*b1[j] + (g[j+3] - x)*(1.0f/(g[j+3]-g[j+1]))*b1[j+1];
  #pragma unroll
  for (int j=0; j<8; ++j)
    bs[j] = (x - g[j])*(1.0f/(g[j+3]-g[j]))*b2[j] + (g[j+4] - x)*(1.0f/(g[j+4]-g[j+1]))*b2[j+1];
}

template<int NT, bool FINAL>
__launch_bounds__(256)
__global__ void kan_kernel(const float* __restrict__ Xin, const u16* __restrict__ Bmat,
                           float* __restrict__ Yout, void* __restrict__ Obuf,
                           const void* __restrict__ slope, const int* __restrict__ flag)
{
  constexpr int MAXC = (NT+3)/4;
  __shared__ __attribute__((aligned(16))) float xs[64][80];
  __shared__ __attribute__((aligned(16))) u16 abase[64][192];
  __shared__ __attribute__((aligned(16))) u16 asp[64][128];
  const int isbf = *flag;
  const int tid = threadIdx.x;
  const size_t r0 = (size_t)blockIdx.x * 64;

  for (int idx=tid; idx<5120; idx+=256) ((float*)xs)[idx] = Xin[r0*80 + idx];
  __syncthreads();
  for (int idx=tid; idx<6144; idx+=256){
    const int row = idx/96, m = idx - row*96;
    float v = 0.f;
    if (m < 80){ const float xv = xs[row][m]; v = xv * sigm(xv); }
    const u16 hi = f2bf(v);
    abase[row][2*m] = hi; abase[row][2*m+1] = f2bf(v - bf2f(hi));
  }
  __syncthreads();

  const int w = tid>>6, l = tid&63, m16 = l&15, q4 = l>>4;
  const int cbase = NT>>2, rem = NT&3;
  const int cnt  = cbase + ((w < rem) ? 1 : 0);
  const int ntlo = w*cbase + ((w < rem) ? w : rem);
  floatx4 acc[MAXC][4];
  #pragma unroll
  for (int j=0;j<MAXC;++j) for (int s=0;s<4;++s){ floatx4 z={0.f,0.f,0.f,0.f}; acc[j][s]=z; }

  #pragma unroll 1
  for (int ks=0; ks<6; ++ks){
    short8 a[4];
    #pragma unroll
    for (int s=0;s<4;++s) a[s] = *(const short8*)&abase[s*16+m16][ks*32 + q4*8];
    #pragma unroll
    for (int j=0;j<MAXC;++j){
      if (j < cnt){
        const short8 b = *(const short8*)&Bmat[(size_t)((ntlo+j)*16+m16)*1472 + ks*32 + q4*8];
        #pragma unroll
        for (int s=0;s<4;++s) acc[j][s] = __builtin_amdgcn_mfma_f32_16x16x32_bf16(a[s], b, acc[j][s], 0, 0, 0);
      }
    }
  }
  #pragma unroll 1
  for (int c=0; c<10; ++c){
    __syncthreads();
    for (int idx=tid; idx<512; idx+=256){
      const int row = idx>>3, il = idx&7;
      const float xv = xs[row][c*8 + il];
      float bs[8]; spline8(xv, bs);
      union { u16 us[16]; short8 v2[2]; } pk;
      #pragma unroll
      for (int j=0; j<8; ++j){ const u16 hi = f2bf(bs[j]); pk.us[2*j] = hi; pk.us[2*j+1] = f2bf(bs[j] - bf2f(hi)); }
      *(short8*)&asp[row][il*16]     = pk.v2[0];
      *(short8*)&asp[row][il*16 + 8] = pk.v2[1];
    }
    __syncthreads();
    #pragma unroll 1
    for (int ks=0; ks<4; ++ks){
      short8 a[4];
      #pragma unroll
      for (int s=0;s<4;++s) a[s] = *(const short8*)&asp[s*16+m16][ks*32 + q4*8];
      const int kg = 192 + c*128 + ks*32 + q4*8;
      #pragma unroll
      for (int j=0;j<MAXC;++j){
        if (j < cnt){
          const short8 b = *(const short8*)&Bmat[(size_t)((ntlo+j)*16+m16)*1472 + kg];
          #pragma unroll
          for (int s=0;s<4;++s) acc[j][s] = __builtin_amdgcn_mfma_f32_16x16x32_bf16(a[s], b, acc[j][s], 0, 0, 0);
        }
      }
    }
  }

  #pragma unroll
  for (int j=0;j<MAXC;++j){
    if (j < cnt){
      const int col = (ntlo+j)*16 + m16;
      #pragma unroll
      for (int s=0;s<4;++s){
        #pragma unroll
        for (int rg=0; rg<4; ++rg){
          const size_t row = r0 + s*16 + q4*4 + rg;
          const float v = acc[j][s][rg];
          if constexpr (!FINAL){
            Yout[row*80 + col] = v;
          } else {
            if (col < 257){
              const float sl = lodf(slope, col, isbf);
              const float o = 1.2f * sigm(sl*v);
              if (isbf) ((u16*)Obuf)[row*257 + col] = f2bf(o);
              else      ((float*)Obuf)[row*257 + col] = o;
            }
          }
        }
      }
    }
  }
}

// ============================= launcher =============================
extern "C" void kernel_launch(void* const* d_in, const int* in_sizes, int n_in,
                              void* d_out, int out_size, void* d_ws, size_t ws_size,
                              hipStream_t stream)
{
  (void)in_sizes; (void)n_in; (void)out_size; (void)ws_size;
  const void* x     = d_in[0];
  const void* f0Wih = d_in[2];  const void* f0Whh = d_in[3];
  const void* f0bih = d_in[4];  const void* f0bhh = d_in[5];
  const void* f1Wih = d_in[6];  const void* f1Whh = d_in[7];
  const void* f1bih = d_in[8];  const void* f1bhh = d_in[9];
  const void* b0Wih = d_in[10]; const void* b0Whh = d_in[11];
  const void* b0bih = d_in[12]; const void* b0bhh = d_in[13];
  const void* b1Wih = d_in[14]; const void* b1Whh = d_in[15];
  const void* b1bih = d_in[16]; const void* b1bhh = d_in[17];
  const void* k1b   = d_in[18]; const void* k1s   = d_in[19]; const void* k1sc = d_in[20];
  const void* k2b   = d_in[21]; const void* k2s   = d_in[22]; const void* k2sc = d_in[23];
  const void* slope = d_in[24];

  char* ws = (char*)d_ws;
  int*   flag  = (int*)(ws + OFF_FLAG);
  float* gi    = (float*)(ws + OFF_GI);
  float* hcat  = (float*)(ws + OFF_HCAT);
  float* k1out = (float*)(ws + OFF_KO);
  u16* B1a = (u16*)(ws + OFF_B1A);
  u16* B1b = (u16*)(ws + OFF_B1B);
  u16* B2  = (u16*)(ws + OFF_B2);
  u16* B3  = (u16*)(ws + OFF_B3);

  detect_kernel<<<1, 64, 0, stream>>>((const u16*)x, flag);
  prep_kernel<<<1300, 256, 0, stream>>>(f0Wih, b0Wih, k1b, k1s, k1sc, k2b, k2s, k2sc, flag, B1a, B1b, B2, B3);
  g1_kernel<<<1200, 256, 0, stream>>>(x, B1a, B1b, f0bih, b0bih, flag, gi);
  gru_kernel<<<128, 256, 0, stream>>>(gi,
      f0Whh, f0bhh, f1Wih, f1Whh, f1bih, f1bhh,
      b0Whh, b0bhh, b1Wih, b1Whh, b1bih, b1bhh, flag, hcat);
  kan_kernel<5,  false><<<600, 256, 0, stream>>>(hcat, B2, k1out, nullptr, nullptr, flag);
  kan_kernel<17, true ><<<600, 256, 0, stream>>>(k1out, B3, nullptr, d_out, slope, flag);
}

// Round 5
// 723.492 us; speedup vs baseline: 1.3144x; 1.0704x over previous
//
#include <hip/hip_runtime.h>
#include <cstdint>
#include <cstddef>

typedef unsigned short u16;
typedef unsigned int u32;
typedef __attribute__((ext_vector_type(8))) short short8;
typedef __attribute__((ext_vector_type(4))) float floatx4;
typedef __attribute__((ext_vector_type(2))) float float2v;

#define NROWS 38400   // B*T = 64*600

// ---- workspace layout (bytes) ----
#define OFF_FLAG 0u
#define OFF_GI   64u           // [2][38400][120] f32 = 36,864,000
#define OFF_HCAT 36864064u     // [38400][80] f32    = 12,288,000
#define OFF_B1A  49152064u     // [256][576] bf16    =    294,912
#define OFF_B1B  49446976u     // [256][576] bf16    =    294,912
#define OFF_B2   49741888u     // [80][1472] bf16    =    235,520
#define OFF_B3   49977408u     // [272][1472] bf16   =    800,768  (end ~50.78 MB)

template<int N> struct IC { static constexpr int v = N; };

__device__ inline float bf2f(u16 u){ union{u32 i; float f;} v; v.i = ((u32)u)<<16; return v.f; }
__device__ inline u16 f2bf(float f){
  u32 u = __float_as_uint(f);
  return (u16)((u + 0x7FFFu + ((u>>16)&1u)) >> 16);   // RNE
}
__device__ inline float lodf(const void* p, size_t i, int isbf){
  return isbf ? bf2f(((const u16*)p)[i]) : ((const float*)p)[i];
}
__device__ inline float rcpf(float x){ return __builtin_amdgcn_rcpf(x); }
__device__ inline float sigm(float x){ return rcpf(1.0f+__expf(-x)); }
__device__ inline float tanh_(float x){
  float e = __expf(-2.0f*fabsf(x)); float t = (1.0f-e)*rcpf(1.0f+e); return x<0.f ? -t : t;
}

// ============================= detect input dtype (bf16 vs f32) =============================
__global__ void detect_kernel(const u16* __restrict__ xx, int* __restrict__ flag){
  const int l = threadIdx.x;
  const u16 w = xx[2*l];
  const int e = (w>>7)&0xFF;
  const unsigned long long m = __ballot(e >= 100 && e <= 133);
  if (l == 0) *flag = (__popcll(m) >= 32) ? 1 : 0;   // 1 = bf16
}

// ============================= prep: build padded bf16 B^T matrices =============================
__global__ void prep_kernel(const void* __restrict__ f0Wih, const void* __restrict__ b0Wih,
                            const void* __restrict__ k1b, const void* __restrict__ k1s, const void* __restrict__ k1sc,
                            const void* __restrict__ k2b, const void* __restrict__ k2s, const void* __restrict__ k2sc,
                            const int* __restrict__ flag,
                            u16* __restrict__ B1a, u16* __restrict__ B1b,
                            u16* __restrict__ B2, u16* __restrict__ B3)
{
  const int isbf = *flag;
  const int idx = blockIdx.x*256 + threadIdx.x;
  if (idx < 73728){
    const int j = idx/288, k = idx - j*288;
    float w = 0.f;
    if (k < 257 && j < 240)
      w = (j < 120) ? lodf(f0Wih, (size_t)j*257+k, isbf) : lodf(b0Wih, (size_t)(j-120)*257+k, isbf);
    const u16 hi = f2bf(w); const u16 lo = f2bf(w - bf2f(hi));
    B1a[(size_t)j*576 + 2*k] = hi; B1a[(size_t)j*576 + 2*k+1] = hi;
    B1b[(size_t)j*576 + 2*k] = lo; B1b[(size_t)j*576 + 2*k+1] = 0;
  } else if (idx < 132608){
    const int t = idx - 73728; const int n = t/736, m = t - n*736;
    float v = 0.f;
    if (m < 80) v = lodf(k1b, (size_t)n*80+m, isbf);
    else if (m >= 96){ const int m2 = m-96, i = m2>>3, g = m2&7;
      v = lodf(k1s, ((size_t)n*80+i)*8+g, isbf) * lodf(k1sc, (size_t)n*80+i, isbf); }
    const u16 vv = f2bf(v);
    B2[(size_t)n*1472 + 2*m] = vv; B2[(size_t)n*1472 + 2*m+1] = vv;
  } else {
    const int t = idx - 132608; const int n = t/736, m = t - n*736;
    float v = 0.f;
    if (n < 257){
      if (m < 80) v = lodf(k2b, (size_t)n*80+m, isbf);
      else if (m >= 96){ const int m2 = m-96, i = m2>>3, g = m2&7;
        v = lodf(k2s, ((size_t)n*80+i)*8+g, isbf) * lodf(k2sc, (size_t)n*80+i, isbf); }
    }
    const u16 vv = f2bf(v);
    B3[(size_t)n*1472 + 2*m] = vv; B3[(size_t)n*1472 + 2*m+1] = vv;
  }
}

// ============================= G1: gi = x @ Wih^T + bih, MFMA, nt-split across waves =============================
__launch_bounds__(256)
__global__ void g1_kernel(const void* __restrict__ x, const u16* __restrict__ B1a, const u16* __restrict__ B1b,
                          const void* __restrict__ f0bih, const void* __restrict__ b0bih,
                          const int* __restrict__ flag, float* __restrict__ gi)
{
  __shared__ __attribute__((aligned(16))) u16 As[32][576];
  const int isbf = *flag;
  const int tid = threadIdx.x;
  const size_t r0 = (size_t)blockIdx.x * 32;
  {
    const int row = tid>>3, kk = tid&7;
    #pragma unroll
    for (int it=0; it<36; ++it){
      const int k = kk + it*8;
      const float v = (k < 257) ? lodf(x, (r0+row)*257 + k, isbf) : 0.f;
      const u16 hi = f2bf(v);
      As[row][2*k] = hi; As[row][2*k+1] = f2bf(v - bf2f(hi));
    }
  }
  __syncthreads();
  const int w = tid>>6, l = tid&63, m16 = l&15, q4 = l>>4;
  // NT=15 split {4,4,4,3}
  const int cnt = (w<3)?4:3;
  const int ntlo = w*4;
  floatx4 acc[4][2];
  #pragma unroll
  for (int j=0;j<4;++j) for (int s=0;s<2;++s){ floatx4 z={0.f,0.f,0.f,0.f}; acc[j][s]=z; }
  #pragma unroll 1
  for (int ks=0; ks<18; ++ks){
    const short8 a0 = *(const short8*)&As[m16][ks*32 + q4*8];
    const short8 a1 = *(const short8*)&As[16+m16][ks*32 + q4*8];
    #pragma unroll
    for (int j=0;j<4;++j){
      if (j < cnt){
        const int nt = ntlo + j;
        const short8 ba = *(const short8*)&B1a[(size_t)(nt*16+m16)*576 + ks*32 + q4*8];
        acc[j][0] = __builtin_amdgcn_mfma_f32_16x16x32_bf16(a0, ba, acc[j][0], 0, 0, 0);
        acc[j][1] = __builtin_amdgcn_mfma_f32_16x16x32_bf16(a1, ba, acc[j][1], 0, 0, 0);
        if (!isbf){
          const short8 bb = *(const short8*)&B1b[(size_t)(nt*16+m16)*576 + ks*32 + q4*8];
          acc[j][0] = __builtin_amdgcn_mfma_f32_16x16x32_bf16(a0, bb, acc[j][0], 0, 0, 0);
          acc[j][1] = __builtin_amdgcn_mfma_f32_16x16x32_bf16(a1, bb, acc[j][1], 0, 0, 0);
        }
      }
    }
  }
  #pragma unroll
  for (int j=0;j<4;++j){
    if (j < cnt){
      const int col = (ntlo+j)*16 + m16;
      if (col < 240){
        const int dsel = (col < 120) ? 0 : 1;
        const int jj = (col < 120) ? col : col-120;
        const float bias = (col < 120) ? lodf(f0bih, col, isbf) : lodf(b0bih, col-120, isbf);
        #pragma unroll
        for (int s=0;s<2;++s){
          #pragma unroll
          for (int rg=0; rg<4; ++rg){
            const size_t row = r0 + s*16 + q4*4 + rg;
            gi[((size_t)dsel*NROWS + row)*120 + jj] = acc[j][s][rg] + bias;
          }
        }
      }
    }
  }
}

// ============================= GRU =============================
// R4 post-mortem: LDS-broadcast matvec worked (344->258us). Still latency-bound:
// per-cell ~1019 cy vs ~430 issue. This round halves matvec issue+chain with
// v_pk_fma_f32 (CDNA full-rate packed fp32): 120 v_fmac -> 60 pk-FMA, even/odd
// split chains (fp32 reassoc noise ~1e-6, absmax budget 7.8e-3).
#define PIN_W() do { \
    _Pragma("unroll") \
    for (int k_ = 0; k_ < 20; ++k_) \
      asm volatile("" : "+v"(WA[k_]), "+v"(WB[k_]), "+v"(WC[k_])); \
    asm volatile("" : "+v"(bA), "+v"(bB), "+v"(bC)); \
  } while (0)

__device__ inline void stage_chunk32(const char* __restrict__ gid, int4* dst, int c, int d, int bat, int l)
{
  const long long rbase = (long long)bat*600 + (d ? (568 - 32*c) : (32*c));
  const long long base = rbase * 480;
  const long long lim = (long long)NROWS * 480;
  int4 v[15];
  #pragma unroll
  for (int j=0; j<15; ++j){
    const long long off = base + (long long)(j*64 + l)*16;
    int4 z; z.x=0; z.y=0; z.z=0; z.w=0;
    v[j] = (off >= 0 && off+16 <= lim) ? *(const int4*)(gid + off) : z;
  }
  #pragma unroll
  for (int j=0; j<15; ++j) dst[j*64 + l] = v[j];
}

__launch_bounds__(256, 1)
__global__ void gru_kernel(const float* __restrict__ gi,
  const void* __restrict__ f0Whh, const void* __restrict__ f0bhh,
  const void* __restrict__ f1Wih, const void* __restrict__ f1Whh, const void* __restrict__ f1bih, const void* __restrict__ f1bhh,
  const void* __restrict__ b0Whh, const void* __restrict__ b0bhh,
  const void* __restrict__ b1Wih, const void* __restrict__ b1Whh, const void* __restrict__ b1bih, const void* __restrict__ b1bhh,
  const int* __restrict__ flag, float* __restrict__ hcat)
{
  __shared__ int4 chunkbuf[2][960];                                   // 30720 B
  __shared__ __attribute__((aligned(16))) float hbuf[2][64][40];      // 20480 B
  __shared__ __attribute__((aligned(16))) float h0buf[2][4][40];      // 1280 B
  __shared__ __attribute__((aligned(16))) float gi1buf[2][4][3][40];  // 3840 B
  __shared__ __attribute__((aligned(16))) float h0st[40];             // layer0 h state (broadcast row)
  __shared__ __attribute__((aligned(16))) float h1st[40];             // layer1 h state
  const int isbf = *flag;
  const int tid = threadIdx.x, l = tid&63;
  // provably wave-uniform role id (SGPR) -> uniform branches around barriers
  const int w = __builtin_amdgcn_readfirstlane(tid) >> 6;
  const int blk = blockIdx.x, d = blk>>6, bat = blk&63;
  const int li = (l < 40) ? l : 39;
  const char* gid = (const char*)(gi + (size_t)d*NROWS*120);

  // Schedule (152 iterations, one barrier each; chunk = 32 ticks = 8 iters):
  //  w0: i<150        : layer0 cells for ticks 4i..4i+3   (reads chunkbuf[(i>>3)&1])
  //  w1: 1<=i<=150    : layer1 input matvec of h0buf[(i-1)&1]
  //  w2: i>=2         : layer1 cells for ticks 4(i-2)..+3 -> hbuf
  //  w3: (i&7)==0     : stage chunk (i>>3)+1 (<=18); (i&15)==2,i>=18: flush hcat window
  if (w == 3){
    stage_chunk32(gid, &chunkbuf[0][0], 0, d, bat, l);
    __syncthreads();
    #pragma unroll 1
    for (int i=0; i<152; ++i){
      if ((i & 7) == 0){ const int c1 = (i>>3) + 1; if (c1 <= 18) stage_chunk32(gid, &chunkbuf[c1&1][0], c1, d, bat, l); }
      if ((i & 15) == 2 && i >= 18){
        const int m = (i>>4) - 1;        // window m: ticks 64m..64m+63, parity m&1
        const int t0 = 64*m;
        const int4* src = (const int4*)&hbuf[m&1][0][0];
        #pragma unroll
        for (int q=0; q<10; ++q){
          const int f = q*64 + l;
          const int t = f/10, j4 = f - 10*t;
          int4 v = src[t*10 + j4];
          *(int4*)&hcat[((size_t)bat*600 + t0 + t)*80 + d*40 + j4*4] = v;
        }
      }
      __syncthreads();
    }
  } else {
    // ---------------- compute waves: load role weights into VGPR pairs ----------------
    const void *Wsrc = 0, *bsrc = 0;
    if (w == 0){ Wsrc = d ? b0Whh : f0Whh; bsrc = d ? b0bhh : f0bhh; }
    else if (w == 1){ Wsrc = d ? b1Wih : f1Wih; bsrc = d ? b1bih : f1bih; }
    else { Wsrc = d ? b1Whh : f1Whh; bsrc = d ? b1bhh : f1bhh; }

    float2v WA[20], WB[20], WC[20];
    #pragma unroll
    for (int k=0; k<20; ++k){
      WA[k][0] = lodf(Wsrc, (size_t)(     li)*40 + 2*k,   isbf);
      WA[k][1] = lodf(Wsrc, (size_t)(     li)*40 + 2*k+1, isbf);
      WB[k][0] = lodf(Wsrc, (size_t)(40 + li)*40 + 2*k,   isbf);
      WB[k][1] = lodf(Wsrc, (size_t)(40 + li)*40 + 2*k+1, isbf);
      WC[k][0] = lodf(Wsrc, (size_t)(80 + li)*40 + 2*k,   isbf);
      WC[k][1] = lodf(Wsrc, (size_t)(80 + li)*40 + 2*k+1, isbf);
    }
    float bA = lodf(bsrc, li, isbf), bB = lodf(bsrc, 40+li, isbf), bC = lodf(bsrc, 80+li, isbf);
    float hs = 0.f;

    // broadcast matvec via packed fp32 FMA: h read from 160B LDS row with
    // wave-uniform addresses (ds_read_b128 broadcast); 60 v_pk_fma_f32 total.
    auto mv3B = [&](const float* hrow, float& oa, float& ob, float& oc){
      float2v a2 = {bA, 0.f}, b2 = {bB, 0.f}, c2 = {bC, 0.f};
      #pragma unroll
      for (int kq=0; kq<10; ++kq){
        const floatx4 hv = *(const floatx4*)(hrow + kq*4);
        float2v h0; h0[0]=hv[0]; h0[1]=hv[1];
        float2v h1; h1[0]=hv[2]; h1[1]=hv[3];
        asm("v_pk_fma_f32 %0, %1, %2, %0" : "+v"(a2) : "v"(WA[2*kq  ]), "v"(h0));
        asm("v_pk_fma_f32 %0, %1, %2, %0" : "+v"(b2) : "v"(WB[2*kq  ]), "v"(h0));
        asm("v_pk_fma_f32 %0, %1, %2, %0" : "+v"(c2) : "v"(WC[2*kq  ]), "v"(h0));
        asm("v_pk_fma_f32 %0, %1, %2, %0" : "+v"(a2) : "v"(WA[2*kq+1]), "v"(h1));
        asm("v_pk_fma_f32 %0, %1, %2, %0" : "+v"(b2) : "v"(WB[2*kq+1]), "v"(h1));
        asm("v_pk_fma_f32 %0, %1, %2, %0" : "+v"(c2) : "v"(WC[2*kq+1]), "v"(h1));
      }
      oa = a2[0] + a2[1]; ob = b2[0] + b2[1]; oc = c2[0] + c2[1];
    };
    auto cellB = [&](const float* hrow, float hsv, float gA, float gB, float gC) -> float {
      float ar, az, an;
      mv3B(hrow, ar, az, an);
      const float r = sigm(gA + ar), z = sigm(gB + az);
      const float n = tanh_(gC + r*an);
      return (1.f - z)*n + z*hsv;
    };

    if (w == 0){
      if (l < 40) h0st[l] = 0.f;       // own-wave state init (no cross-wave reader)
      __syncthreads();
      #pragma unroll 1
      for (int i=0; i<152; ++i){
        PIN_W();
        if (i < 150){
          const int cc = (i>>3)&1;
          const int ta = (4*i)&31;
          const float* base = (const float*)&chunkbuf[cc][0];
          // hoist all 12 gate inputs for the period (one LDS latency batch)
          float gin[4][3];
          #pragma unroll
          for (int t=0; t<4; ++t){
            const float* r = base + (d ? (31-(ta+t)) : (ta+t))*120;
            gin[t][0]=r[li]; gin[t][1]=r[40+li]; gin[t][2]=r[80+li];
          }
          #pragma unroll
          for (int t=0; t<4; ++t){
            hs = cellB(h0st, hs, gin[t][0], gin[t][1], gin[t][2]);
            if (l < 40){ h0st[l] = hs; h0buf[i&1][t][l] = hs; }
          }
        }
        __syncthreads();
      }
    } else if (w == 1){
      __syncthreads();
      #pragma unroll 1
      for (int i=0; i<152; ++i){
        PIN_W();
        if (i >= 1 && i <= 150){
          const int p = (i-1)&1;
          #pragma unroll
          for (int t=0; t<4; ++t){
            float oa, ob, oc;
            mv3B(&h0buf[p][t][0], oa, ob, oc);
            if (l < 40){
              gi1buf[i&1][t][0][l]=oa; gi1buf[i&1][t][1][l]=ob; gi1buf[i&1][t][2][l]=oc;
            }
          }
        }
        __syncthreads();
      }
    } else {
      if (l < 40) h1st[l] = 0.f;
      __syncthreads();
      #pragma unroll 1
      for (int i=0; i<152; ++i){
        PIN_W();
        if (i >= 2){
          const int p = (i-1)&1;
          // hoist the 12 gate inputs (written by w1 last period; barrier between)
          float gin[4][3];
          #pragma unroll
          for (int t=0; t<4; ++t){
            gin[t][0]=gi1buf[p][t][0][li]; gin[t][1]=gi1buf[p][t][1][li]; gin[t][2]=gi1buf[p][t][2][li];
          }
          const int ta2 = 4*(i-2);
          const int wp = (ta2>>6)&1, sa = ta2&63;
          #pragma unroll
          for (int t=0; t<4; ++t){
            hs = cellB(h1st, hs, gin[t][0], gin[t][1], gin[t][2]);
            if (l < 40){ h1st[l] = hs; hbuf[wp][sa+t][l] = hs; }
          }
        }
        __syncthreads();
      }
    }
  }
  // flush final window (window 9: ticks 576..599, parity 1); all waves have passed
  // the final in-loop barrier (153 barriers each), so hbuf writes are visible.
  if (tid < 240){
    const int t = tid/10, j4 = tid - 10*t;
    const int4* src = (const int4*)&hbuf[1][0][0];
    int4 v = src[t*10 + j4];
    *(int4*)&hcat[((size_t)bat*600 + 576 + t)*80 + d*40 + j4*4] = v;
  }
}

// ============================= KAN: fused kan1+kan2 (kan2 row needs only kan1's same row) =====
__device__ inline void spline8(float x, float* bs)
{
  float g[12];
  #pragma unroll
  for (int j=0; j<12; ++j) g[j] = (float)(j-3)*0.4f - 1.0f;
  float b0[11];
  #pragma unroll
  for (int j=0; j<11; ++j) b0[j] = (x >= g[j] && x < g[j+1]) ? 1.f : 0.f;
  float b1[10];
  #pragma unroll
  for (int j=0; j<10; ++j)
    b1[j] = (x - g[j])*(1.0f/(g[j+1]-g[j]))*b0[j] + (g[j+2] - x)*(1.0f/(g[j+2]-g[j+1]))*b0[j+1];
  float b2[9];
  #pragma unroll
  for (int j=0; j<9; ++j)
    b2[j] = (x - g[j])*(1.0f/(g[j+2]-g[j]))*b1[j] + (g[j+3] - x)*(1.0f/(g[j+3]-g[j+1]))*b1[j+1];
  #pragma unroll
  for (int j=0; j<8; ++j)
    bs[j] = (x - g[j])*(1.0f/(g[j+3]-g[j]))*b2[j] + (g[j+4] - x)*(1.0f/(g[j+4]-g[j+1]))*b2[j+1];
}

__launch_bounds__(256)
__global__ void kan_fused_kernel(const float* __restrict__ Xin,
                                 const u16* __restrict__ B2mat, const u16* __restrict__ B3mat,
                                 void* __restrict__ Obuf,
                                 const void* __restrict__ slope, const int* __restrict__ flag)
{
  __shared__ __attribute__((aligned(16))) float xs[64][80];     // inputs; overwritten by kan1 outputs
  __shared__ __attribute__((aligned(16))) u16 abase[64][192];
  __shared__ __attribute__((aligned(16))) u16 asp[64][128];
  const int isbf = *flag;
  const int tid = threadIdx.x;
  const size_t r0 = (size_t)blockIdx.x * 64;
  const int w = tid>>6, l = tid&63, m16 = l&15, q4 = l>>4;

  for (int idx=tid; idx<5120; idx+=256) ((float*)xs)[idx] = Xin[r0*80 + idx];
  __syncthreads();

  auto phase = [&](auto ntc, auto fc, const u16* __restrict__ Bmat){
    constexpr int NT   = decltype(ntc)::v;
    constexpr int FINAL = decltype(fc)::v;
    constexpr int MAXC = (NT+3)/4;
    // silu(xs) -> abase (hi/lo bf16 pairs)
    for (int idx=tid; idx<6144; idx+=256){
      const int row = idx/96, m = idx - row*96;
      float v = 0.f;
      if (m < 80){ const float xv = xs[row][m]; v = xv * sigm(xv); }
      const u16 hi = f2bf(v);
      abase[row][2*m] = hi; abase[row][2*m+1] = f2bf(v - bf2f(hi));
    }
    __syncthreads();

    const int cbase = NT>>2, rem = NT&3;
    const int cnt  = cbase + ((w < rem) ? 1 : 0);
    const int ntlo = w*cbase + ((w < rem) ? w : rem);
    floatx4 acc[MAXC][4];
    #pragma unroll
    for (int j=0;j<MAXC;++j) for (int s=0;s<4;++s){ floatx4 z={0.f,0.f,0.f,0.f}; acc[j][s]=z; }

    #pragma unroll 1
    for (int ks=0; ks<6; ++ks){
      short8 a[4];
      #pragma unroll
      for (int s=0;s<4;++s) a[s] = *(const short8*)&abase[s*16+m16][ks*32 + q4*8];
      #pragma unroll
      for (int j=0;j<MAXC;++j){
        if (j < cnt){
          const short8 b = *(const short8*)&Bmat[(size_t)((ntlo+j)*16+m16)*1472 + ks*32 + q4*8];
          #pragma unroll
          for (int s=0;s<4;++s) acc[j][s] = __builtin_amdgcn_mfma_f32_16x16x32_bf16(a[s], b, acc[j][s], 0, 0, 0);
        }
      }
    }
    #pragma unroll 1
    for (int c=0; c<10; ++c){
      __syncthreads();
      for (int idx=tid; idx<512; idx+=256){
        const int row = idx>>3, il = idx&7;
        const float xv = xs[row][c*8 + il];
        float bs[8]; spline8(xv, bs);
        union { u16 us[16]; short8 v2[2]; } pk;
        #pragma unroll
        for (int j=0; j<8; ++j){ const u16 hi = f2bf(bs[j]); pk.us[2*j] = hi; pk.us[2*j+1] = f2bf(bs[j] - bf2f(hi)); }
        *(short8*)&asp[row][il*16]     = pk.v2[0];
        *(short8*)&asp[row][il*16 + 8] = pk.v2[1];
      }
      __syncthreads();
      #pragma unroll 1
      for (int ks=0; ks<4; ++ks){
        short8 a[4];
        #pragma unroll
        for (int s=0;s<4;++s) a[s] = *(const short8*)&asp[s*16+m16][ks*32 + q4*8];
        const int kg = 192 + c*128 + ks*32 + q4*8;
        #pragma unroll
        for (int j=0;j<MAXC;++j){
          if (j < cnt){
            const short8 b = *(const short8*)&Bmat[(size_t)((ntlo+j)*16+m16)*1472 + kg];
            #pragma unroll
            for (int s=0;s<4;++s) acc[j][s] = __builtin_amdgcn_mfma_f32_16x16x32_bf16(a[s], b, acc[j][s], 0, 0, 0);
          }
        }
      }
    }
    // epilogue: kan1 -> overwrite xs in LDS (xs inputs are dead after c=9);
    // kan2 -> activation + store to Obuf
    __syncthreads();   // ensure all waves done reading xs (spline c=9) before overwrite
    #pragma unroll
    for (int j=0;j<MAXC;++j){
      if (j < cnt){
        const int col = (ntlo+j)*16 + m16;
        #pragma unroll
        for (int s=0;s<4;++s){
          #pragma unroll
          for (int rg=0; rg<4; ++rg){
            const int row = s*16 + q4*4 + rg;
            const float v = acc[j][s][rg];
            if constexpr (!FINAL){
              xs[row][col] = v;          // col < 80 for NT=5
            } else {
              if (col < 257){
                const float sl = lodf(slope, col, isbf);
                const float o = 1.2f * sigm(sl*v);
                if (isbf) ((u16*)Obuf)[(r0+row)*257 + col] = f2bf(o);
                else      ((float*)Obuf)[(r0+row)*257 + col] = o;
              }
            }
          }
        }
      }
    }
    __syncthreads();   // xs writes visible before next phase's silu reads
  };

  phase(IC<5>{},  IC<0>{}, B2mat);
  phase(IC<17>{}, IC<1>{}, B3mat);
}

// ============================= launcher =============================
extern "C" void kernel_launch(void* const* d_in, const int* in_sizes, int n_in,
                              void* d_out, int out_size, void* d_ws, size_t ws_size,
                              hipStream_t stream)
{
  (void)in_sizes; (void)n_in; (void)out_size; (void)ws_size;
  const void* x     = d_in[0];
  const void* f0Wih = d_in[2];  const void* f0Whh = d_in[3];
  const void* f0bih = d_in[4];  const void* f0bhh = d_in[5];
  const void* f1Wih = d_in[6];  const void* f1Whh = d_in[7];
  const void* f1bih = d_in[8];  const void* f1bhh = d_in[9];
  const void* b0Wih = d_in[10]; const void* b0Whh = d_in[11];
  const void* b0bih = d_in[12]; const void* b0bhh = d_in[13];
  const void* b1Wih = d_in[14]; const void* b1Whh = d_in[15];
  const void* b1bih = d_in[16]; const void* b1bhh = d_in[17];
  const void* k1b   = d_in[18]; const void* k1s   = d_in[19]; const void* k1sc = d_in[20];
  const void* k2b   = d_in[21]; const void* k2s   = d_in[22]; const void* k2sc = d_in[23];
  const void* slope = d_in[24];

  char* ws = (char*)d_ws;
  int*   flag  = (int*)(ws + OFF_FLAG);
  float* gi    = (float*)(ws + OFF_GI);
  float* hcat  = (float*)(ws + OFF_HCAT);
  u16* B1a = (u16*)(ws + OFF_B1A);
  u16* B1b = (u16*)(ws + OFF_B1B);
  u16* B2  = (u16*)(ws + OFF_B2);
  u16* B3  = (u16*)(ws + OFF_B3);

  detect_kernel<<<1, 64, 0, stream>>>((const u16*)x, flag);
  prep_kernel<<<1300, 256, 0, stream>>>(f0Wih, b0Wih, k1b, k1s, k1sc, k2b, k2s, k2sc, flag, B1a, B1b, B2, B3);
  g1_kernel<<<1200, 256, 0, stream>>>(x, B1a, B1b, f0bih, b0bih, flag, gi);
  gru_kernel<<<128, 256, 0, stream>>>(gi,
      f0Whh, f0bhh, f1Wih, f1Whh, f1bih, f1bhh,
      b0Whh, b0bhh, b1Wih, b1Whh, b1bih, b1bhh, flag, hcat);
  kan_fused_kernel<<<600, 256, 0, stream>>>(hcat, B2, B3, d_out, slope, flag);
}

// Round 7
// 647.766 us; speedup vs baseline: 1.4681x; 1.1169x over previous
//
#include <hip/hip_runtime.h>
#include <cstdint>
#include <cstddef>

typedef unsigned short u16;
typedef unsigned int u32;
typedef __attribute__((ext_vector_type(8))) short short8;
typedef __attribute__((ext_vector_type(4))) float floatx4;
typedef __attribute__((ext_vector_type(2))) float float2v;

#define NROWS 38400   // B*T = 64*600

// ---- workspace layout (bytes) ----
#define OFF_FLAG 0u
#define OFF_GI   64u           // [2][38400][120] f32 = 36,864,000
#define OFF_HCAT 36864064u     // [38400][80] f32    = 12,288,000
#define OFF_B1A  49152064u     // [256][576] bf16    =    294,912
#define OFF_B1B  49446976u     // [256][576] bf16    =    294,912
#define OFF_B2   49741888u     // [80][1472] bf16    =    235,520
#define OFF_B3   49977408u     // [272][1472] bf16   =    800,768  (end ~50.78 MB)

template<int N> struct IC { static constexpr int v = N; };

__device__ inline float bf2f(u16 u){ union{u32 i; float f;} v; v.i = ((u32)u)<<16; return v.f; }
__device__ inline u16 f2bf(float f){
  u32 u = __float_as_uint(f);
  return (u16)((u + 0x7FFFu + ((u>>16)&1u)) >> 16);   // RNE
}
__device__ inline float lodf(const void* p, size_t i, int isbf){
  return isbf ? bf2f(((const u16*)p)[i]) : ((const float*)p)[i];
}
__device__ inline float rcpf(float x){ return __builtin_amdgcn_rcpf(x); }
__device__ inline float sigm(float x){ return rcpf(1.0f+__expf(-x)); }
__device__ inline float tanh_(float x){
  float e = __expf(-2.0f*fabsf(x)); float t = (1.0f-e)*rcpf(1.0f+e); return x<0.f ? -t : t;
}

// ============================= detect input dtype (bf16 vs f32) =============================
__global__ void detect_kernel(const u16* __restrict__ xx, int* __restrict__ flag){
  const int l = threadIdx.x;
  const u16 w = xx[2*l];
  const int e = (w>>7)&0xFF;
  const unsigned long long m = __ballot(e >= 100 && e <= 133);
  if (l == 0) *flag = (__popcll(m) >= 32) ? 1 : 0;   // 1 = bf16
}

// ============================= prep: build padded bf16 B^T matrices =============================
__global__ void prep_kernel(const void* __restrict__ f0Wih, const void* __restrict__ b0Wih,
                            const void* __restrict__ k1b, const void* __restrict__ k1s, const void* __restrict__ k1sc,
                            const void* __restrict__ k2b, const void* __restrict__ k2s, const void* __restrict__ k2sc,
                            const int* __restrict__ flag,
                            u16* __restrict__ B1a, u16* __restrict__ B1b,
                            u16* __restrict__ B2, u16* __restrict__ B3)
{
  const int isbf = *flag;
  const int idx = blockIdx.x*256 + threadIdx.x;
  if (idx < 73728){
    const int j = idx/288, k = idx - j*288;
    float w = 0.f;
    if (k < 257 && j < 240)
      w = (j < 120) ? lodf(f0Wih, (size_t)j*257+k, isbf) : lodf(b0Wih, (size_t)(j-120)*257+k, isbf);
    const u16 hi = f2bf(w); const u16 lo = f2bf(w - bf2f(hi));
    B1a[(size_t)j*576 + 2*k] = hi; B1a[(size_t)j*576 + 2*k+1] = hi;
    B1b[(size_t)j*576 + 2*k] = lo; B1b[(size_t)j*576 + 2*k+1] = 0;
  } else if (idx < 132608){
    const int t = idx - 73728; const int n = t/736, m = t - n*736;
    float v = 0.f;
    if (m < 80) v = lodf(k1b, (size_t)n*80+m, isbf);
    else if (m >= 96){ const int m2 = m-96, i = m2>>3, g = m2&7;
      v = lodf(k1s, ((size_t)n*80+i)*8+g, isbf) * lodf(k1sc, (size_t)n*80+i, isbf); }
    const u16 vv = f2bf(v);
    B2[(size_t)n*1472 + 2*m] = vv; B2[(size_t)n*1472 + 2*m+1] = vv;
  } else {
    const int t = idx - 132608; const int n = t/736, m = t - n*736;
    float v = 0.f;
    if (n < 257){
      if (m < 80) v = lodf(k2b, (size_t)n*80+m, isbf);
      else if (m >= 96){ const int m2 = m-96, i = m2>>3, g = m2&7;
        v = lodf(k2s, ((size_t)n*80+i)*8+g, isbf) * lodf(k2sc, (size_t)n*80+i, isbf); }
    }
    const u16 vv = f2bf(v);
    B3[(size_t)n*1472 + 2*m] = vv; B3[(size_t)n*1472 + 2*m+1] = vv;
  }
}

// ============================= G1: gi = x @ Wih^T + bih, MFMA, nt-split across waves =============================
// As padded to 584 u16/row (1168 B = 292 dw == 4 mod 32): the 16-lane MFMA
// A-frag reads spread across 8 bank groups (2-way = free) instead of all
// hitting bank 0 (8-wide conflict at the old 576-u16 stride).
__launch_bounds__(256)
__global__ void g1_kernel(const void* __restrict__ x, const u16* __restrict__ B1a, const u16* __restrict__ B1b,
                          const void* __restrict__ f0bih, const void* __restrict__ b0bih,
                          const int* __restrict__ flag, float* __restrict__ gi)
{
  __shared__ __attribute__((aligned(16))) u16 As[32][584];
  const int isbf = *flag;
  const int tid = threadIdx.x;
  const size_t r0 = (size_t)blockIdx.x * 32;
  {
    const int row = tid>>3, kk = tid&7;
    #pragma unroll
    for (int it=0; it<36; ++it){
      const int k = kk + it*8;
      const float v = (k < 257) ? lodf(x, (r0+row)*257 + k, isbf) : 0.f;
      const u16 hi = f2bf(v);
      As[row][2*k] = hi; As[row][2*k+1] = f2bf(v - bf2f(hi));
    }
  }
  __syncthreads();
  const int w = tid>>6, l = tid&63, m16 = l&15, q4 = l>>4;
  // NT=15 split {4,4,4,3}
  const int cnt = (w<3)?4:3;
  const int ntlo = w*4;
  floatx4 acc[4][2];
  #pragma unroll
  for (int j=0;j<4;++j) for (int s=0;s<2;++s){ floatx4 z={0.f,0.f,0.f,0.f}; acc[j][s]=z; }
  #pragma unroll 1
  for (int ks=0; ks<18; ++ks){
    const short8 a0 = *(const short8*)&As[m16][ks*32 + q4*8];
    const short8 a1 = *(const short8*)&As[16+m16][ks*32 + q4*8];
    #pragma unroll
    for (int j=0;j<4;++j){
      if (j < cnt){
        const int nt = ntlo + j;
        const short8 ba = *(const short8*)&B1a[(size_t)(nt*16+m16)*576 + ks*32 + q4*8];
        acc[j][0] = __builtin_amdgcn_mfma_f32_16x16x32_bf16(a0, ba, acc[j][0], 0, 0, 0);
        acc[j][1] = __builtin_amdgcn_mfma_f32_16x16x32_bf16(a1, ba, acc[j][1], 0, 0, 0);
        if (!isbf){
          const short8 bb = *(const short8*)&B1b[(size_t)(nt*16+m16)*576 + ks*32 + q4*8];
          acc[j][0] = __builtin_amdgcn_mfma_f32_16x16x32_bf16(a0, bb, acc[j][0], 0, 0, 0);
          acc[j][1] = __builtin_amdgcn_mfma_f32_16x16x32_bf16(a1, bb, acc[j][1], 0, 0, 0);
        }
      }
    }
  }
  #pragma unroll
  for (int j=0;j<4;++j){
    if (j < cnt){
      const int col = (ntlo+j)*16 + m16;
      if (col < 240){
        const int dsel = (col < 120) ? 0 : 1;
        const int jj = (col < 120) ? col : col-120;
        const float bias = (col < 120) ? lodf(f0bih, col, isbf) : lodf(b0bih, col-120, isbf);
        #pragma unroll
        for (int s=0;s<2;++s){
          #pragma unroll
          for (int rg=0; rg<4; ++rg){
            const size_t row = r0 + s*16 + q4*4 + rg;
            gi[((size_t)dsel*NROWS + row)*120 + jj] = acc[j][s][rg] + bias;
          }
        }
      }
    }
  }
}

// ============================= GRU =============================
#define PIN_W() do { \
    _Pragma("unroll") \
    for (int k_ = 0; k_ < 20; ++k_) \
      asm volatile("" : "+v"(WA[k_]), "+v"(WB[k_]), "+v"(WC[k_])); \
    asm volatile("" : "+v"(bA), "+v"(bB), "+v"(bC)); \
  } while (0)

__device__ inline void stage_chunk32(const char* __restrict__ gid, int4* dst, int c, int d, int bat, int l)
{
  const long long rbase = (long long)bat*600 + (d ? (568 - 32*c) : (32*c));
  const long long base = rbase * 480;
  const long long lim = (long long)NROWS * 480;
  int4 v[15];
  #pragma unroll
  for (int j=0; j<15; ++j){
    const long long off = base + (long long)(j*64 + l)*16;
    int4 z; z.x=0; z.y=0; z.z=0; z.w=0;
    v[j] = (off >= 0 && off+16 <= lim) ? *(const int4*)(gid + off) : z;
  }
  #pragma unroll
  for (int j=0; j<15; ++j) dst[j*64 + l] = v[j];
}

__launch_bounds__(256, 1)
__global__ void gru_kernel(const float* __restrict__ gi,
  const void* __restrict__ f0Whh, const void* __restrict__ f0bhh,
  const void* __restrict__ f1Wih, const void* __restrict__ f1Whh, const void* __restrict__ f1bih, const void* __restrict__ f1bhh,
  const void* __restrict__ b0Whh, const void* __restrict__ b0bhh,
  const void* __restrict__ b1Wih, const void* __restrict__ b1Whh, const void* __restrict__ b1bih, const void* __restrict__ b1bhh,
  const int* __restrict__ flag, float* __restrict__ hcat)
{
  __shared__ int4 chunkbuf[2][960];                                   // 30720 B
  __shared__ __attribute__((aligned(16))) float hbuf[2][64][40];      // 20480 B
  __shared__ __attribute__((aligned(16))) float h0buf[2][4][40];      // 1280 B
  __shared__ __attribute__((aligned(16))) float gi1buf[2][4][3][40];  // 3840 B
  __shared__ __attribute__((aligned(16))) float h0st[40];             // layer0 h state (broadcast row)
  __shared__ __attribute__((aligned(16))) float h1st[40];             // layer1 h state
  const int isbf = *flag;
  const int tid = threadIdx.x, l = tid&63;
  // provably wave-uniform role id (SGPR) -> uniform branches around barriers
  const int w = __builtin_amdgcn_readfirstlane(tid) >> 6;
  const int blk = blockIdx.x, d = blk>>6, bat = blk&63;
  const int li = (l < 40) ? l : 39;
  const char* gid = (const char*)(gi + (size_t)d*NROWS*120);

  // Schedule (152 iterations, one barrier each; chunk = 32 ticks = 8 iters):
  //  w0: i<150        : layer0 cells for ticks 4i..4i+3   (reads chunkbuf[(i>>3)&1])
  //  w1: 1<=i<=150    : layer1 input matvec of h0buf[(i-1)&1]
  //  w2: i>=2         : layer1 cells for ticks 4(i-2)..+3 -> hbuf
  //  w3: (i&7)==0     : stage chunk (i>>3)+1 (<=18); (i&15)==2,i>=18: flush hcat window
  if (w == 3){
    stage_chunk32(gid, &chunkbuf[0][0], 0, d, bat, l);
    __syncthreads();
    #pragma unroll 1
    for (int i=0; i<152; ++i){
      if ((i & 7) == 0){ const int c1 = (i>>3) + 1; if (c1 <= 18) stage_chunk32(gid, &chunkbuf[c1&1][0], c1, d, bat, l); }
      if ((i & 15) == 2 && i >= 18){
        const int m = (i>>4) - 1;        // window m: ticks 64m..64m+63, parity m&1
        const int t0 = 64*m;
        const int4* src = (const int4*)&hbuf[m&1][0][0];
        #pragma unroll
        for (int q=0; q<10; ++q){
          const int f = q*64 + l;
          const int t = f/10, j4 = f - 10*t;
          int4 v = src[t*10 + j4];
          *(int4*)&hcat[((size_t)bat*600 + t0 + t)*80 + d*40 + j4*4] = v;
        }
      }
      __syncthreads();
    }
  } else {
    // ---------------- compute waves: load role weights into VGPR pairs ----------------
    const void *Wsrc = 0, *bsrc = 0;
    if (w == 0){ Wsrc = d ? b0Whh : f0Whh; bsrc = d ? b0bhh : f0bhh; }
    else if (w == 1){ Wsrc = d ? b1Wih : f1Wih; bsrc = d ? b1bih : f1bih; }
    else { Wsrc = d ? b1Whh : f1Whh; bsrc = d ? b1bhh : f1bhh; }

    float2v WA[20], WB[20], WC[20];
    #pragma unroll
    for (int k=0; k<20; ++k){
      WA[k][0] = lodf(Wsrc, (size_t)(     li)*40 + 2*k,   isbf);
      WA[k][1] = lodf(Wsrc, (size_t)(     li)*40 + 2*k+1, isbf);
      WB[k][0] = lodf(Wsrc, (size_t)(40 + li)*40 + 2*k,   isbf);
      WB[k][1] = lodf(Wsrc, (size_t)(40 + li)*40 + 2*k+1, isbf);
      WC[k][0] = lodf(Wsrc, (size_t)(80 + li)*40 + 2*k,   isbf);
      WC[k][1] = lodf(Wsrc, (size_t)(80 + li)*40 + 2*k+1, isbf);
    }
    float bA = lodf(bsrc, li, isbf), bB = lodf(bsrc, 40+li, isbf), bC = lodf(bsrc, 80+li, isbf);
    float hs = 0.f;

    // broadcast matvec via packed fp32 FMA: h read from 160B LDS row with
    // wave-uniform addresses (ds_read_b128 broadcast); 60 v_pk_fma_f32 total.
    auto mv3B = [&](const float* hrow, float& oa, float& ob, float& oc){
      float2v a2 = {bA, 0.f}, b2 = {bB, 0.f}, c2 = {bC, 0.f};
      #pragma unroll
      for (int kq=0; kq<10; ++kq){
        const floatx4 hv = *(const floatx4*)(hrow + kq*4);
        float2v h0; h0[0]=hv[0]; h0[1]=hv[1];
        float2v h1; h1[0]=hv[2]; h1[1]=hv[3];
        asm("v_pk_fma_f32 %0, %1, %2, %0" : "+v"(a2) : "v"(WA[2*kq  ]), "v"(h0));
        asm("v_pk_fma_f32 %0, %1, %2, %0" : "+v"(b2) : "v"(WB[2*kq  ]), "v"(h0));
        asm("v_pk_fma_f32 %0, %1, %2, %0" : "+v"(c2) : "v"(WC[2*kq  ]), "v"(h0));
        asm("v_pk_fma_f32 %0, %1, %2, %0" : "+v"(a2) : "v"(WA[2*kq+1]), "v"(h1));
        asm("v_pk_fma_f32 %0, %1, %2, %0" : "+v"(b2) : "v"(WB[2*kq+1]), "v"(h1));
        asm("v_pk_fma_f32 %0, %1, %2, %0" : "+v"(c2) : "v"(WC[2*kq+1]), "v"(h1));
      }
      oa = a2[0] + a2[1]; ob = b2[0] + b2[1]; oc = c2[0] + c2[1];
    };
    auto cellB = [&](const float* hrow, float hsv, float gA, float gB, float gC) -> float {
      float ar, az, an;
      mv3B(hrow, ar, az, an);
      const float r = sigm(gA + ar), z = sigm(gB + az);
      const float n = tanh_(gC + r*an);
      return (1.f - z)*n + z*hsv;
    };

    if (w == 0){
      if (l < 40) h0st[l] = 0.f;       // own-wave state init (no cross-wave reader)
      __syncthreads();
      #pragma unroll 1
      for (int i=0; i<152; ++i){
        PIN_W();
        if (i < 150){
          const int cc = (i>>3)&1;
          const int ta = (4*i)&31;
          const float* base = (const float*)&chunkbuf[cc][0];
          // hoist all 12 gate inputs for the period (one LDS latency batch)
          float gin[4][3];
          #pragma unroll
          for (int t=0; t<4; ++t){
            const float* r = base + (d ? (31-(ta+t)) : (ta+t))*120;
            gin[t][0]=r[li]; gin[t][1]=r[40+li]; gin[t][2]=r[80+li];
          }
          #pragma unroll
          for (int t=0; t<4; ++t){
            hs = cellB(h0st, hs, gin[t][0], gin[t][1], gin[t][2]);
            if (l < 40){ h0st[l] = hs; h0buf[i&1][t][l] = hs; }
          }
        }
        __syncthreads();
      }
    } else if (w == 1){
      __syncthreads();
      #pragma unroll 1
      for (int i=0; i<152; ++i){
        PIN_W();
        if (i >= 1 && i <= 150){
          const int p = (i-1)&1;
          #pragma unroll
          for (int t=0; t<4; ++t){
            float oa, ob, oc;
            mv3B(&h0buf[p][t][0], oa, ob, oc);
            if (l < 40){
              gi1buf[i&1][t][0][l]=oa; gi1buf[i&1][t][1][l]=ob; gi1buf[i&1][t][2][l]=oc;
            }
          }
        }
        __syncthreads();
      }
    } else {
      if (l < 40) h1st[l] = 0.f;
      __syncthreads();
      #pragma unroll 1
      for (int i=0; i<152; ++i){
        PIN_W();
        if (i >= 2){
          const int p = (i-1)&1;
          // hoist the 12 gate inputs (written by w1 last period; barrier between)
          float gin[4][3];
          #pragma unroll
          for (int t=0; t<4; ++t){
            gin[t][0]=gi1buf[p][t][0][li]; gin[t][1]=gi1buf[p][t][1][li]; gin[t][2]=gi1buf[p][t][2][li];
          }
          const int ta2 = 4*(i-2);
          const int wp = (ta2>>6)&1, sa = ta2&63;
          #pragma unroll
          for (int t=0; t<4; ++t){
            hs = cellB(h1st, hs, gin[t][0], gin[t][1], gin[t][2]);
            if (l < 40){ h1st[l] = hs; hbuf[wp][sa+t][l] = hs; }
          }
        }
        __syncthreads();
      }
    }
  }
  // flush final window (window 9: ticks 576..599, parity 1); all waves have passed
  // the final in-loop barrier (153 barriers each), so hbuf writes are visible.
  if (tid < 240){
    const int t = tid/10, j4 = tid - 10*t;
    const int4* src = (const int4*)&hbuf[1][0][0];
    int4 v = src[t*10 + j4];
    *(int4*)&hcat[((size_t)bat*600 + 576 + t)*80 + d*40 + j4*4] = v;
  }
}

// ============================= KAN: fused kan1+kan2 =============================
// R5 counters: SQ_LDS_BANK_CONFLICT=2.47e7, MfmaUtil 5.7%, HBM 3.7% -> conflict+
// latency bound. Fixes: (1) pad abase/asp rows to stride==4 mod 32 dwords
// (2-way bank aliasing = free, vs 8-wide at the old power-of-2 strides);
// (2) double-buffered register prefetch of the global B fragments so each
// k-step's ~250cy L2 latency hides under the previous k-step's MFMAs / the
// spline VALU + barriers.
__device__ inline void spline8(float x, float* bs)
{
  float g[12];
  #pragma unroll
  for (int j=0; j<12; ++j) g[j] = (float)(j-3)*0.4f - 1.0f;
  float b0[11];
  #pragma unroll
  for (int j=0; j<11; ++j) b0[j] = (x >= g[j] && x < g[j+1]) ? 1.f : 0.f;
  float b1[10];
  #pragma unroll
  for (int j=0; j<10; ++j)
    b1[j] = (x - g[j])*(1.0f/(g[j+1]-g[j]))*b0[j] + (g[j+2] - x)*(1.0f/(g[j+2]-g[j+1]))*b0[j+1];
  float b2[9];
  #pragma unroll
  for (int j=0; j<9; ++j)
    b2[j] = (x - g[j])*(1.0f/(g[j+2]-g[j]))*b1[j] + (g[j+3] - x)*(1.0f/(g[j+3]-g[j+1]))*b1[j+1];
  #pragma unroll
  for (int j=0; j<8; ++j)
    bs[j] = (x - g[j])*(1.0f/(g[j+3]-g[j]))*b2[j] + (g[j+4] - x)*(1.0f/(g[j+4]-g[j+1]))*b2[j+1];
}

__launch_bounds__(256)
__global__ void kan_fused_kernel(const float* __restrict__ Xin,
                                 const u16* __restrict__ B2mat, const u16* __restrict__ B3mat,
                                 void* __restrict__ Obuf,
                                 const void* __restrict__ slope, const int* __restrict__ flag)
{
  __shared__ __attribute__((aligned(16))) float xs[64][80];       // 20480 B; overwritten by kan1 out
  __shared__ __attribute__((aligned(16))) u16 abase[64][200];     // 25600 B (stride 400B == 4 mod 32 dw)
  __shared__ __attribute__((aligned(16))) u16 asp[64][136];       // 17408 B (stride 272B == 4 mod 32 dw)
  const int isbf = *flag;
  const int tid = threadIdx.x;
  const size_t r0 = (size_t)blockIdx.x * 64;
  const int w = tid>>6, l = tid&63, m16 = l&15, q4 = l>>4;

  for (int idx=tid; idx<5120; idx+=256) ((float*)xs)[idx] = Xin[r0*80 + idx];
  __syncthreads();

  auto phase = [&](auto ntc, auto fc, const u16* __restrict__ Bmat){
    constexpr int NT   = decltype(ntc)::v;
    constexpr int FINAL = decltype(fc)::v;
    constexpr int MAXC = (NT+3)/4;
    const int cbase = NT>>2, rem = NT&3;
    const int cnt  = cbase + ((w < rem) ? 1 : 0);
    const int ntlo = w*cbase + ((w < rem) ? w : rem);

    short8 bz;
    #pragma unroll
    for (int q=0;q<8;++q) bz[q]=0;
    short8 bcur[MAXC], bnxt[MAXC];
    #pragma unroll
    for (int j=0;j<MAXC;++j){ bcur[j]=bz; bnxt[j]=bz; }

    // prefetch B(base, ks=0) -- hides under silu + barrier
    #pragma unroll
    for (int j=0;j<MAXC;++j) if (j<cnt)
      bcur[j] = *(const short8*)&Bmat[(size_t)((ntlo+j)*16+m16)*1472 + q4*8];

    // silu(xs) -> abase (hi/lo bf16 pairs)
    for (int idx=tid; idx<6144; idx+=256){
      const int row = idx/96, m = idx - row*96;
      float v = 0.f;
      if (m < 80){ const float xv = xs[row][m]; v = xv * sigm(xv); }
      const u16 hi = f2bf(v);
      abase[row][2*m] = hi; abase[row][2*m+1] = f2bf(v - bf2f(hi));
    }
    __syncthreads();

    floatx4 acc[MAXC][4];
    #pragma unroll
    for (int j=0;j<MAXC;++j) for (int s=0;s<4;++s){ floatx4 z={0.f,0.f,0.f,0.f}; acc[j][s]=z; }

    #pragma unroll 1
    for (int ks=0; ks<6; ++ks){
      #pragma unroll
      for (int j=0;j<MAXC;++j) if (j<cnt && ks<5)
        bnxt[j] = *(const short8*)&Bmat[(size_t)((ntlo+j)*16+m16)*1472 + (ks+1)*32 + q4*8];
      short8 a[4];
      #pragma unroll
      for (int s=0;s<4;++s) a[s] = *(const short8*)&abase[s*16+m16][ks*32 + q4*8];
      #pragma unroll
      for (int j=0;j<MAXC;++j){
        if (j < cnt){
          #pragma unroll
          for (int s=0;s<4;++s) acc[j][s] = __builtin_amdgcn_mfma_f32_16x16x32_bf16(a[s], bcur[j], acc[j][s], 0, 0, 0);
        }
      }
      #pragma unroll
      for (int j=0;j<MAXC;++j) bcur[j] = bnxt[j];
    }
    #pragma unroll 1
    for (int c=0; c<10; ++c){
      // prefetch B(c, ks=0) -- hides under spline compute + 2 barriers
      #pragma unroll
      for (int j=0;j<MAXC;++j) if (j<cnt)
        bcur[j] = *(const short8*)&Bmat[(size_t)((ntlo+j)*16+m16)*1472 + 192 + c*128 + q4*8];
      __syncthreads();
      for (int idx=tid; idx<512; idx+=256){
        const int row = idx>>3, il = idx&7;
        const float xv = xs[row][c*8 + il];
        float bs[8]; spline8(xv, bs);
        union { u16 us[16]; short8 v2[2]; } pk;
        #pragma unroll
        for (int j=0; j<8; ++j){ const u16 hi = f2bf(bs[j]); pk.us[2*j] = hi; pk.us[2*j+1] = f2bf(bs[j] - bf2f(hi)); }
        *(short8*)&asp[row][il*16]     = pk.v2[0];
        *(short8*)&asp[row][il*16 + 8] = pk.v2[1];
      }
      __syncthreads();
      #pragma unroll 1
      for (int ks=0; ks<4; ++ks){
        #pragma unroll
        for (int j=0;j<MAXC;++j) if (j<cnt && ks<3)
          bnxt[j] = *(const short8*)&Bmat[(size_t)((ntlo+j)*16+m16)*1472 + 192 + c*128 + (ks+1)*32 + q4*8];
        short8 a[4];
        #pragma unroll
        for (int s=0;s<4;++s) a[s] = *(const short8*)&asp[s*16+m16][ks*32 + q4*8];
        #pragma unroll
        for (int j=0;j<MAXC;++j){
          if (j < cnt){
            #pragma unroll
            for (int s=0;s<4;++s) acc[j][s] = __builtin_amdgcn_mfma_f32_16x16x32_bf16(a[s], bcur[j], acc[j][s], 0, 0, 0);
          }
        }
        #pragma unroll
        for (int j=0;j<MAXC;++j) bcur[j] = bnxt[j];
      }
    }
    // epilogue: kan1 -> overwrite xs in LDS (xs inputs are dead after c=9);
    // kan2 -> activation + store to Obuf
    __syncthreads();   // ensure all waves done reading xs (spline c=9) before overwrite
    #pragma unroll
    for (int j=0;j<MAXC;++j){
      if (j < cnt){
        const int col = (ntlo+j)*16 + m16;
        #pragma unroll
        for (int s=0;s<4;++s){
          #pragma unroll
          for (int rg=0; rg<4; ++rg){
            const int row = s*16 + q4*4 + rg;
            const float v = acc[j][s][rg];
            if constexpr (!FINAL){
              xs[row][col] = v;          // col < 80 for NT=5
            } else {
              if (col < 257){
                const float sl = lodf(slope, col, isbf);
                const float o = 1.2f * sigm(sl*v);
                if (isbf) ((u16*)Obuf)[(r0+row)*257 + col] = f2bf(o);
                else      ((float*)Obuf)[(r0+row)*257 + col] = o;
              }
            }
          }
        }
      }
    }
    __syncthreads();   // xs writes visible before next phase's silu reads
  };

  phase(IC<5>{},  IC<0>{}, B2mat);
  phase(IC<17>{}, IC<1>{}, B3mat);
}

// ============================= launcher =============================
extern "C" void kernel_launch(void* const* d_in, const int* in_sizes, int n_in,
                              void* d_out, int out_size, void* d_ws, size_t ws_size,
                              hipStream_t stream)
{
  (void)in_sizes; (void)n_in; (void)out_size; (void)ws_size;
  const void* x     = d_in[0];
  const void* f0Wih = d_in[2];  const void* f0Whh = d_in[3];
  const void* f0bih = d_in[4];  const void* f0bhh = d_in[5];
  const void* f1Wih = d_in[6];  const void* f1Whh = d_in[7];
  const void* f1bih = d_in[8];  const void* f1bhh = d_in[9];
  const void* b0Wih = d_in[10]; const void* b0Whh = d_in[11];
  const void* b0bih = d_in[12]; const void* b0bhh = d_in[13];
  const void* b1Wih = d_in[14]; const void* b1Whh = d_in[15];
  const void* b1bih = d_in[16]; const void* b1bhh = d_in[17];
  const void* k1b   = d_in[18]; const void* k1s   = d_in[19]; const void* k1sc = d_in[20];
  const void* k2b   = d_in[21]; const void* k2s   = d_in[22]; const void* k2sc = d_in[23];
  const void* slope = d_in[24];

  char* ws = (char*)d_ws;
  int*   flag  = (int*)(ws + OFF_FLAG);
  float* gi    = (float*)(ws + OFF_GI);
  float* hcat  = (float*)(ws + OFF_HCAT);
  u16* B1a = (u16*)(ws + OFF_B1A);
  u16* B1b = (u16*)(ws + OFF_B1B);
  u16* B2  = (u16*)(ws + OFF_B2);
  u16* B3  = (u16*)(ws + OFF_B3);

  detect_kernel<<<1, 64, 0, stream>>>((const u16*)x, flag);
  prep_kernel<<<1300, 256, 0, stream>>>(f0Wih, b0Wih, k1b, k1s, k1sc, k2b, k2s, k2sc, flag, B1a, B1b, B2, B3);
  g1_kernel<<<1200, 256, 0, stream>>>(x, B1a, B1b, f0bih, b0bih, flag, gi);
  gru_kernel<<<128, 256, 0, stream>>>(gi,
      f0Whh, f0bhh, f1Wih, f1Whh, f1bih, f1bhh,
      b0Whh, b0bhh, b1Wih, b1Whh, b1bih, b1bhh, flag, hcat);
  kan_fused_kernel<<<600, 256, 0, stream>>>(hcat, B2, B3, d_out, slope, flag);
}